// Round 1
// baseline (2829.409 us; speedup 1.0000x reference)
//
#include <hip/hip_runtime.h>
#include <hip/hip_bf16.h>
#include <math.h>

// Problem constants
#define B_SZ   4
#define T_LEN  2048
#define DM     1024
#define NH     16
#define DH     64
#define INNER  1024          // NH*DH
#define NROWS  (B_SZ*T_LEN)  // 8192
#define NQ     (NROWS*INNER) // 8,388,608 elements per Q/K/V/Y buffer
#define CH     64            // scan chunk length (timesteps staged in LDS)

// ---------------------------------------------------------------------------
// SGEMM: C[rows x M] = A[rows x K] * B[K x M], 128x128 tile, 8x8 microtile,
// 256 threads. rows covered by gridDim.y*128, M by gridDim.x*128.
// ---------------------------------------------------------------------------
__device__ __forceinline__ void sgemm_body(const float* __restrict__ A,
                                           const float* __restrict__ B,
                                           float* __restrict__ C,
                                           int M, int K,
                                           float (*As)[128], float (*Bs)[128]) {
    const int tid  = threadIdx.x;
    const int tx   = tid & 15;        // 0..15 -> col group
    const int ty   = tid >> 4;        // 0..15 -> row group
    const int arow = tid >> 1;        // 0..127
    const int acol = (tid & 1) * 4;   // 0 or 4
    const int brow = tid >> 5;        // 0..7
    const int bcol = (tid & 31) * 4;  // 0..124

    const float* Ab = A + (blockIdx.y * 128) * K;
    const float* Bb = B + blockIdx.x * 128;

    float acc[8][8];
#pragma unroll
    for (int i = 0; i < 8; i++)
#pragma unroll
        for (int j = 0; j < 8; j++) acc[i][j] = 0.f;

    for (int k0 = 0; k0 < K; k0 += 8) {
        const float4 av = *(const float4*)(Ab + arow * K + k0 + acol);
        const float4 bv = *(const float4*)(Bb + (k0 + brow) * M + bcol);
        __syncthreads();   // previous iteration's reads done before overwrite
        As[acol + 0][arow] = av.x;
        As[acol + 1][arow] = av.y;
        As[acol + 2][arow] = av.z;
        As[acol + 3][arow] = av.w;
        *(float4*)&Bs[brow][bcol] = bv;
        __syncthreads();
#pragma unroll
        for (int k = 0; k < 8; k++) {
            float ar[8], br[8];
            *(float4*)&ar[0] = *(const float4*)&As[k][ty * 8];
            *(float4*)&ar[4] = *(const float4*)&As[k][ty * 8 + 4];
            *(float4*)&br[0] = *(const float4*)&Bs[k][tx * 8];
            *(float4*)&br[4] = *(const float4*)&Bs[k][tx * 8 + 4];
#pragma unroll
            for (int i = 0; i < 8; i++)
#pragma unroll
                for (int j = 0; j < 8; j++) acc[i][j] += ar[i] * br[j];
        }
    }

    float* Cb = C + (blockIdx.y * 128 + ty * 8) * M + blockIdx.x * 128 + tx * 8;
#pragma unroll
    for (int i = 0; i < 8; i++)
#pragma unroll
        for (int j = 0; j < 8; j++) Cb[i * M + j] = acc[i][j];
}

__global__ __launch_bounds__(256) void sgemm128(const float* __restrict__ A,
                                                const float* __restrict__ B,
                                                float* __restrict__ C,
                                                int M, int K) {
    __shared__ float As[8][128];
    __shared__ float Bs[8][128];
    sgemm_body(A, B, C, M, K, As, Bs);
}

// Fused QKV: blockIdx.z selects the weight matrix / output buffer.
__global__ __launch_bounds__(256) void qkv_gemm(const float* __restrict__ x,
                                                const float* __restrict__ Wq,
                                                const float* __restrict__ Wk,
                                                const float* __restrict__ Wv,
                                                float* __restrict__ Q,
                                                float* __restrict__ K_,
                                                float* __restrict__ V,
                                                int M, int K) {
    __shared__ float As[8][128];
    __shared__ float Bs[8][128];
    const float* Bm = (blockIdx.z == 0) ? Wq : ((blockIdx.z == 1) ? Wk : Wv);
    float*       Cm = (blockIdx.z == 0) ? Q  : ((blockIdx.z == 1) ? K_ : V);
    sgemm_body(x, Bm, Cm, M, K, As, Bs);
}

// ---------------------------------------------------------------------------
// Gates: alpha = sigmoid(x@Wa + ba), beta = sigmoid(x@Wb + bb).  One block
// (256 threads) per row n; x row staged in LDS; 16 segments x 16 heads.
// ---------------------------------------------------------------------------
__global__ __launch_bounds__(256) void gates_kernel(const float* __restrict__ x,
                                                    const float* __restrict__ Wa,
                                                    const float* __restrict__ ba,
                                                    const float* __restrict__ Wb,
                                                    const float* __restrict__ bb,
                                                    float* __restrict__ Alpha,
                                                    float* __restrict__ Beta) {
    const int n = blockIdx.x;
    const int t = threadIdx.x;
    __shared__ float xs[DM];
    __shared__ float red[2][16][16];

    ((float4*)xs)[t] = ((const float4*)(x + n * DM))[t];
    __syncthreads();

    const int h = t & 15, seg = t >> 4;   // 16 segments of 64 k's
    float pa = 0.f, pb = 0.f;
    const int k0 = seg * 64;
#pragma unroll 8
    for (int k = k0; k < k0 + 64; k++) {
        const float xv = xs[k];
        pa += xv * Wa[k * NH + h];
        pb += xv * Wb[k * NH + h];
    }
    red[0][seg][h] = pa;
    red[1][seg][h] = pb;
    __syncthreads();

    if (t < 32) {
        const int g = t >> 4, hh = t & 15;
        float s = 0.f;
#pragma unroll
        for (int sg = 0; sg < 16; sg++) s += red[g][sg][hh];
        s += (g == 0) ? ba[hh] : bb[hh];
        const float sig = 1.f / (1.f + __expf(-s));
        if (g == 0) Alpha[n * NH + hh] = sig;
        else        Beta[n * NH + hh]  = sig;
    }
}

// ---------------------------------------------------------------------------
// K row L2-normalize: rows of 64, one wave per row, 4 waves/block.
// ---------------------------------------------------------------------------
__global__ __launch_bounds__(256) void knorm_kernel(float* __restrict__ K) {
    const int row  = blockIdx.x * 4 + (threadIdx.x >> 6);
    const int lane = threadIdx.x & 63;
    float v = K[row * DH + lane];
    float ss = v * v;
#pragma unroll
    for (int m = 32; m >= 1; m >>= 1) ss += __shfl_xor(ss, m, 64);
    const float scale = 1.f / fmaxf(sqrtf(ss), 1e-12f);
    K[row * DH + lane] = v * scale;
}

// ---------------------------------------------------------------------------
// Sequential scan.  64 blocks (one per (b,h)), 64 threads (one per state
// row).  Thread i holds S[i][0..63] in VGPRs.  q/k/v/alpha/beta for CH=64
// timesteps staged in LDS per chunk (bulk coalesced global loads).
//   S_ij = a*S_ij + (b*v_i)*k_j ;  y_i = sum_j S_ij * q_j   (post-update S)
// Y written in-place over Q (safe: chunk's q already staged in LDS).
// ---------------------------------------------------------------------------
__global__ __launch_bounds__(64) void scan_kernel(const float* __restrict__ Q,
                                                  const float* __restrict__ K,
                                                  const float* __restrict__ V,
                                                  const float* __restrict__ Alpha,
                                                  const float* __restrict__ Beta,
                                                  const float* __restrict__ state_in,
                                                  float* __restrict__ Y,
                                                  float* __restrict__ state_out) {
    const int blk  = blockIdx.x;      // 0..63
    const int b    = blk >> 4;
    const int h    = blk & 15;
    const int lane = threadIdx.x;     // 0..63

    __shared__ float s_kq[CH][64][2]; // [t][j][{k,q}] -> ds_read_b64 broadcast
    __shared__ float s_v[CH][64];
    __shared__ float s_ab[CH][2];

    float S[64];
    {
        const float* st = state_in + ((b * NH + h) * DH + lane) * DH;
#pragma unroll
        for (int j = 0; j < 64; j++) S[j] = st[j];
    }

    for (int c = 0; c < T_LEN / CH; c++) {
        const int t0 = c * CH;
        __syncthreads();  // protect LDS from previous chunk's readers
        // ---- stage chunk ----
#pragma unroll 4
        for (int t = 0; t < CH; t++) {
            const int g = ((b * T_LEN + t0 + t) * NH + h) * DH + lane;
            s_kq[t][lane][0] = K[g];
            s_kq[t][lane][1] = Q[g];
            s_v[t][lane]     = V[g];
        }
        {
            const int ga = (b * T_LEN + t0 + lane) * NH + h;  // lane == step
            s_ab[lane][0] = Alpha[ga];
            s_ab[lane][1] = Beta[ga];
        }
        __syncthreads();
        // ---- 64 sequential steps ----
        for (int t = 0; t < CH; t++) {
            const float a  = s_ab[t][0];
            const float bt = s_ab[t][1];
            const float bv = bt * s_v[t][lane];
            float y0 = 0.f, y1 = 0.f, y2 = 0.f, y3 = 0.f;
#pragma unroll
            for (int j = 0; j < 64; j += 4) {
                float k0 = s_kq[t][j + 0][0], q0 = s_kq[t][j + 0][1];
                float k1 = s_kq[t][j + 1][0], q1 = s_kq[t][j + 1][1];
                float k2 = s_kq[t][j + 2][0], q2 = s_kq[t][j + 2][1];
                float k3 = s_kq[t][j + 3][0], q3 = s_kq[t][j + 3][1];
                S[j + 0] = a * S[j + 0] + bv * k0;  y0 += S[j + 0] * q0;
                S[j + 1] = a * S[j + 1] + bv * k1;  y1 += S[j + 1] * q1;
                S[j + 2] = a * S[j + 2] + bv * k2;  y2 += S[j + 2] * q2;
                S[j + 3] = a * S[j + 3] + bv * k3;  y3 += S[j + 3] * q3;
            }
            const int g = ((b * T_LEN + t0 + t) * NH + h) * DH + lane;
            Y[g] = (y0 + y1) + (y2 + y3);
        }
    }

    // final state
    float* so = state_out + ((b * NH + h) * DH + lane) * DH;
#pragma unroll
    for (int j = 0; j < 64; j++) so[j] = S[j];
}

// ---------------------------------------------------------------------------
extern "C" void kernel_launch(void* const* d_in, const int* in_sizes, int n_in,
                              void* d_out, int out_size, void* d_ws, size_t ws_size,
                              hipStream_t stream) {
    const float* x     = (const float*)d_in[0];
    const float* state = (const float*)d_in[1];
    const float* Wq    = (const float*)d_in[2];
    const float* Wk    = (const float*)d_in[3];
    const float* Wv    = (const float*)d_in[4];
    const float* Wa    = (const float*)d_in[5];
    const float* ba    = (const float*)d_in[6];
    const float* Wb    = (const float*)d_in[7];
    const float* bb    = (const float*)d_in[8];
    const float* Wo    = (const float*)d_in[9];

    float* ws    = (float*)d_ws;
    float* Q     = ws;                 // 8192x1024, later overwritten by Y
    float* Kb    = ws + (size_t)NQ;
    float* V     = ws + 2 * (size_t)NQ;
    float* Alpha = ws + 3 * (size_t)NQ;
    float* Beta  = Alpha + NROWS * NH;

    float* out  = (float*)d_out;       // (B,T,DM)
    float* Sout = out + (size_t)NQ;    // (B,H,D,D)

    // 1) Q/K/V projections (fused, z selects weight)
    qkv_gemm<<<dim3(INNER / 128, NROWS / 128, 3), 256, 0, stream>>>(
        x, Wq, Wk, Wv, Q, Kb, V, INNER, DM);
    // 2) gates
    gates_kernel<<<NROWS, 256, 0, stream>>>(x, Wa, ba, Wb, bb, Alpha, Beta);
    // 3) K normalize (131072 rows, 4 rows/block)
    knorm_kernel<<<(NROWS * NH) / 4, 256, 0, stream>>>(Kb);
    // 4) sequential scan; Y overwrites Q; writes final state to d_out tail
    scan_kernel<<<64, 64, 0, stream>>>(Q, Kb, V, Alpha, Beta, state, Q, Sout);
    // 5) output projection
    sgemm128<<<dim3(DM / 128, NROWS / 128), 256, 0, stream>>>(Q, Wo, out, DM, INNER);
}

// Round 2
// 1580.716 us; speedup vs baseline: 1.7900x; 1.7900x over previous
//
#include <hip/hip_runtime.h>
#include <hip/hip_bf16.h>
#include <math.h>

// Problem constants
#define B_SZ   4
#define T_LEN  2048
#define DM     1024
#define NH     16
#define DH     64
#define INNER  1024          // NH*DH
#define NROWS  (B_SZ*T_LEN)  // 8192
#define NQ     (NROWS*INNER) // elements per Q/K/V/Y buffer
#define CH     64            // chunk length
#define NCH    (T_LEN/CH)    // 32 chunks

// ---------------------------------------------------------------------------
// SGEMM: C[rows x M] = A[rows x K] * B[K x M], 128x128 tile, 8x8 microtile.
// ---------------------------------------------------------------------------
__device__ __forceinline__ void sgemm_body(const float* __restrict__ A,
                                           const float* __restrict__ B,
                                           float* __restrict__ C,
                                           int M, int K,
                                           float (*As)[128], float (*Bs)[128]) {
    const int tid  = threadIdx.x;
    const int tx   = tid & 15;
    const int ty   = tid >> 4;
    const int arow = tid >> 1;
    const int acol = (tid & 1) * 4;
    const int brow = tid >> 5;
    const int bcol = (tid & 31) * 4;

    const float* Ab = A + (blockIdx.y * 128) * K;
    const float* Bb = B + blockIdx.x * 128;

    float acc[8][8];
#pragma unroll
    for (int i = 0; i < 8; i++)
#pragma unroll
        for (int j = 0; j < 8; j++) acc[i][j] = 0.f;

    for (int k0 = 0; k0 < K; k0 += 8) {
        const float4 av = *(const float4*)(Ab + arow * K + k0 + acol);
        const float4 bv = *(const float4*)(Bb + (k0 + brow) * M + bcol);
        __syncthreads();
        As[acol + 0][arow] = av.x;
        As[acol + 1][arow] = av.y;
        As[acol + 2][arow] = av.z;
        As[acol + 3][arow] = av.w;
        *(float4*)&Bs[brow][bcol] = bv;
        __syncthreads();
#pragma unroll
        for (int k = 0; k < 8; k++) {
            float ar[8], br[8];
            *(float4*)&ar[0] = *(const float4*)&As[k][ty * 8];
            *(float4*)&ar[4] = *(const float4*)&As[k][ty * 8 + 4];
            *(float4*)&br[0] = *(const float4*)&Bs[k][tx * 8];
            *(float4*)&br[4] = *(const float4*)&Bs[k][tx * 8 + 4];
#pragma unroll
            for (int i = 0; i < 8; i++)
#pragma unroll
                for (int j = 0; j < 8; j++) acc[i][j] += ar[i] * br[j];
        }
    }

    float* Cb = C + (blockIdx.y * 128 + ty * 8) * M + blockIdx.x * 128 + tx * 8;
#pragma unroll
    for (int i = 0; i < 8; i++)
#pragma unroll
        for (int j = 0; j < 8; j++) Cb[i * M + j] = acc[i][j];
}

__global__ __launch_bounds__(256) void sgemm128(const float* __restrict__ A,
                                                const float* __restrict__ B,
                                                float* __restrict__ C,
                                                int M, int K) {
    __shared__ float As[8][128];
    __shared__ float Bs[8][128];
    sgemm_body(A, B, C, M, K, As, Bs);
}

__global__ __launch_bounds__(256) void qkv_gemm(const float* __restrict__ x,
                                                const float* __restrict__ Wq,
                                                const float* __restrict__ Wk,
                                                const float* __restrict__ Wv,
                                                float* __restrict__ Q,
                                                float* __restrict__ K_,
                                                float* __restrict__ V,
                                                int M, int K) {
    __shared__ float As[8][128];
    __shared__ float Bs[8][128];
    const float* Bm = (blockIdx.z == 0) ? Wq : ((blockIdx.z == 1) ? Wk : Wv);
    float*       Cm = (blockIdx.z == 0) ? Q  : ((blockIdx.z == 1) ? K_ : V);
    sgemm_body(x, Bm, Cm, M, K, As, Bs);
}

// ---------------------------------------------------------------------------
// Gates: alpha = sigmoid(x@Wa + ba), beta = sigmoid(x@Wb + bb).
// ---------------------------------------------------------------------------
__global__ __launch_bounds__(256) void gates_kernel(const float* __restrict__ x,
                                                    const float* __restrict__ Wa,
                                                    const float* __restrict__ ba,
                                                    const float* __restrict__ Wb,
                                                    const float* __restrict__ bb,
                                                    float* __restrict__ Alpha,
                                                    float* __restrict__ Beta) {
    const int n = blockIdx.x;
    const int t = threadIdx.x;
    __shared__ float xs[DM];
    __shared__ float red[2][16][16];

    ((float4*)xs)[t] = ((const float4*)(x + n * DM))[t];
    __syncthreads();

    const int h = t & 15, seg = t >> 4;
    float pa = 0.f, pb = 0.f;
    const int k0 = seg * 64;
#pragma unroll 8
    for (int k = k0; k < k0 + 64; k++) {
        const float xv = xs[k];
        pa += xv * Wa[k * NH + h];
        pb += xv * Wb[k * NH + h];
    }
    red[0][seg][h] = pa;
    red[1][seg][h] = pb;
    __syncthreads();

    if (t < 32) {
        const int g = t >> 4, hh = t & 15;
        float s = 0.f;
#pragma unroll
        for (int sg = 0; sg < 16; sg++) s += red[g][sg][hh];
        s += (g == 0) ? ba[hh] : bb[hh];
        const float sig = 1.f / (1.f + __expf(-s));
        if (g == 0) Alpha[n * NH + hh] = sig;
        else        Beta[n * NH + hh]  = sig;
    }
}

// ---------------------------------------------------------------------------
// K row L2-normalize.
// ---------------------------------------------------------------------------
__global__ __launch_bounds__(256) void knorm_kernel(float* __restrict__ K) {
    const int row  = blockIdx.x * 4 + (threadIdx.x >> 6);
    const int lane = threadIdx.x & 63;
    float v = K[row * DH + lane];
    float ss = v * v;
#pragma unroll
    for (int m = 32; m >= 1; m >>= 1) ss += __shfl_xor(ss, m, 64);
    const float scale = 1.f / fmaxf(sqrtf(ss), 1e-12f);
    K[row * DH + lane] = v * scale;
}

// ---------------------------------------------------------------------------
// Pass A: per-(b,h,chunk) intra-chunk work. 2048 blocks x 256 threads.
//   la_t = inclusive prefix sum of log(alpha) within chunk
//   G = Q K^T ; A[t][s] = 1[s<=t] exp(la_t-la_s) beta_s G[t][s]
//   Y_intra = A V                      -> overwrites V chunk region
//   dS[i][j] = sum_s beta_s exp(la_L-la_s) V[s][i] K[s][j] -> overwrites K
//   Q' = exp(la_t) * Q                 -> overwrites Q (for pass B)
//   chunk decay exp(la_L)              -> overwrites Alpha[t0+63]
// Each block only rewrites global regions it alone reads -> race-free.
// ---------------------------------------------------------------------------
__global__ __launch_bounds__(256) void chunk_intra(float* __restrict__ Q,
                                                   float* __restrict__ K,
                                                   float* __restrict__ V,
                                                   float* __restrict__ Alpha,
                                                   const float* __restrict__ Beta) {
    __shared__ float sQ[64][68];    // later reused to hold A
    __shared__ float sK[64][68];
    __shared__ float sKT[64][68];
    __shared__ float sV[64][68];
    __shared__ __align__(16) float sla[64];
    __shared__ __align__(16) float sexp[64];
    __shared__ __align__(16) float sb[64];
    __shared__ __align__(16) float swd[64];

    const int blk = blockIdx.x;
    const int c = blk & 31, h = (blk >> 5) & 15, b = blk >> 9;
    const int t0 = c * CH;
    const int tid = threadIdx.x;
    const int ty = tid >> 4, tx = tid & 15;
    const size_t rowbase = ((size_t)(b * T_LEN + t0) * NH + h) * DH;

    // ---- stage chunk to LDS ----
#pragma unroll
    for (int r = 0; r < 4; r++) {
        const int row = ty + 16 * r;
        const int col = tx * 4;
        const size_t g = rowbase + (size_t)row * INNER + col;
        const float4 qv = *(const float4*)(Q + g);
        const float4 kv = *(const float4*)(K + g);
        const float4 vv = *(const float4*)(V + g);
        *(float4*)&sQ[row][col] = qv;
        *(float4*)&sK[row][col] = kv;
        *(float4*)&sV[row][col] = vv;
        sKT[col + 0][row] = kv.x;
        sKT[col + 1][row] = kv.y;
        sKT[col + 2][row] = kv.z;
        sKT[col + 3][row] = kv.w;
    }
    if (tid < 64) {
        const int t = tid;
        const size_t ga = (size_t)(b * T_LEN + t0 + t) * NH + h;
        const float a  = Alpha[ga];
        const float bt = Beta[ga];
        float x = logf(a);
#pragma unroll
        for (int off = 1; off < 64; off <<= 1) {
            const float y = __shfl_up(x, off, 64);
            if (t >= off) x += y;
        }
        const float la63 = __shfl(x, 63, 64);
        sla[t]  = x;
        sexp[t] = expf(x);
        sb[t]   = bt;
        swd[t]  = bt * expf(la63 - x);
        if (t == 63) Alpha[ga] = expf(la63);   // chunk total decay for pass B
    }
    __syncthreads();

    const int tt0 = ty * 4, ss0 = tx * 4;

    // ---- G = Q K^T, 4x4 tile per thread ----
    float g4[4][4];
#pragma unroll
    for (int i = 0; i < 4; i++)
#pragma unroll
        for (int j = 0; j < 4; j++) g4[i][j] = 0.f;
    for (int d = 0; d < 64; d += 4) {
        float qa[4][4], ka[4][4];
#pragma unroll
        for (int i = 0; i < 4; i++) *(float4*)&qa[i][0] = *(const float4*)&sQ[tt0 + i][d];
#pragma unroll
        for (int k = 0; k < 4; k++) *(float4*)&ka[k][0] = *(const float4*)&sKT[d + k][ss0];
#pragma unroll
        for (int i = 0; i < 4; i++)
#pragma unroll
            for (int k = 0; k < 4; k++)
#pragma unroll
                for (int j = 0; j < 4; j++) g4[i][j] += qa[i][k] * ka[k][j];
    }

    // ---- write Q' = exp(la_t) * Q back to global (reads sQ only) ----
#pragma unroll
    for (int r = 0; r < 4; r++) {
        const int row = ty + 16 * r;
        const int col = tx * 4;
        float4 qv = *(const float4*)&sQ[row][col];
        const float e = sexp[row];
        qv.x *= e; qv.y *= e; qv.z *= e; qv.w *= e;
        *(float4*)(Q + rowbase + (size_t)row * INNER + col) = qv;
    }
    __syncthreads();   // all sQ reads done before overwriting with A

    // ---- A into sQ ----
    {
#pragma unroll
        for (int i = 0; i < 4; i++) {
            float av[4];
            const int t = tt0 + i;
#pragma unroll
            for (int j = 0; j < 4; j++) {
                const int s = ss0 + j;
                av[j] = (s <= t) ? expf(sla[t] - sla[s]) * sb[s] * g4[i][j] : 0.f;
            }
            *(float4*)&sQ[t][ss0] = *(float4*)&av[0];
        }
    }
    __syncthreads();

    // ---- Y_intra = A V  -> V region ----
    {
        float y4[4][4];
#pragma unroll
        for (int i = 0; i < 4; i++)
#pragma unroll
            for (int j = 0; j < 4; j++) y4[i][j] = 0.f;
        for (int s = 0; s < 64; s += 4) {
            float aa[4][4], vv[4][4];
#pragma unroll
            for (int i = 0; i < 4; i++) *(float4*)&aa[i][0] = *(const float4*)&sQ[tt0 + i][s];
#pragma unroll
            for (int k = 0; k < 4; k++) *(float4*)&vv[k][0] = *(const float4*)&sV[s + k][ss0];
#pragma unroll
            for (int i = 0; i < 4; i++)
#pragma unroll
                for (int k = 0; k < 4; k++)
#pragma unroll
                    for (int j = 0; j < 4; j++) y4[i][j] += aa[i][k] * vv[k][j];
        }
#pragma unroll
        for (int i = 0; i < 4; i++)
            *(float4*)(V + rowbase + (size_t)(tt0 + i) * INNER + ss0) = *(float4*)&y4[i][0];
    }

    // ---- dS = sum_s w_s v_s k_s^T  -> K region ----
    {
        float d4[4][4];
#pragma unroll
        for (int i = 0; i < 4; i++)
#pragma unroll
            for (int j = 0; j < 4; j++) d4[i][j] = 0.f;
        for (int s = 0; s < 64; s += 4) {
            float vv[4][4], kk[4][4], wv[4];
            *(float4*)&wv[0] = *(const float4*)&swd[s];
#pragma unroll
            for (int k = 0; k < 4; k++) *(float4*)&vv[k][0] = *(const float4*)&sV[s + k][tt0];
#pragma unroll
            for (int k = 0; k < 4; k++) *(float4*)&kk[k][0] = *(const float4*)&sK[s + k][ss0];
#pragma unroll
            for (int k = 0; k < 4; k++) {
#pragma unroll
                for (int i = 0; i < 4; i++) {
                    const float wvi = wv[k] * vv[k][i];
#pragma unroll
                    for (int j = 0; j < 4; j++) d4[i][j] += wvi * kk[k][j];
                }
            }
        }
#pragma unroll
        for (int i = 0; i < 4; i++)
            *(float4*)(K + rowbase + (size_t)(tt0 + i) * INNER + ss0) = *(float4*)&d4[i][0];
    }
}

// ---------------------------------------------------------------------------
// Pass B: serial over 32 chunks per (b,h). 64 blocks x 256 threads.
// Thread (w=tid>>6, l=tid&63) holds S[i=l][j=16w..16w+15] in registers.
//   per chunk: partial y[t] = sum_{j slice} Q'[t][j] S[l][j]  (Q' wave-uniform
//   -> scalar loads), cross-wave reduce via LDS, Y += ; then
//   S = decay*S + dS (dS read from K buffer).
// ---------------------------------------------------------------------------
__global__ __launch_bounds__(256) void chunk_scan(const float* __restrict__ Qp,
                                                  const float* __restrict__ DS,
                                                  float* __restrict__ Y,
                                                  const float* __restrict__ Decay,
                                                  const float* __restrict__ state_in,
                                                  float* __restrict__ state_out) {
    __shared__ float red[4][64][64];

    const int blk = blockIdx.x;          // (b,h)
    const int b = blk >> 4, h = blk & 15;
    const int tid = threadIdx.x;
    const int w = __builtin_amdgcn_readfirstlane(tid >> 6);
    const int l = tid & 63;

    float S[16];
    {
        const float* st = state_in + ((size_t)(b * NH + h) * DH + l) * DH + 16 * w;
#pragma unroll
        for (int j4 = 0; j4 < 4; j4++)
            *(float4*)&S[4 * j4] = *(const float4*)(st + 4 * j4);
    }

    for (int c = 0; c < NCH; c++) {
        const int t0 = c * CH;
        const float* qbase = Qp + ((size_t)(b * T_LEN + t0) * NH + h) * DH + 16 * w;
        // ---- partial y's ----
#pragma unroll 4
        for (int t = 0; t < 64; t++) {
            const float* qp = qbase + (size_t)t * INNER;
            const float4 q0 = *(const float4*)(qp + 0);
            const float4 q1 = *(const float4*)(qp + 4);
            const float4 q2 = *(const float4*)(qp + 8);
            const float4 q3 = *(const float4*)(qp + 12);
            float p = q0.x * S[0]  + q0.y * S[1]  + q0.z * S[2]  + q0.w * S[3]
                    + q1.x * S[4]  + q1.y * S[5]  + q1.z * S[6]  + q1.w * S[7]
                    + q2.x * S[8]  + q2.y * S[9]  + q2.z * S[10] + q2.w * S[11]
                    + q3.x * S[12] + q3.y * S[13] + q3.z * S[14] + q3.w * S[15];
            red[w][t][l] = p;
        }
        __syncthreads();
        // ---- reduce across waves + Y RMW ----
        {
            float* yb = Y + ((size_t)(b * T_LEN + t0 + 16 * w) * NH + h) * DH + l;
#pragma unroll 4
            for (int t2 = 0; t2 < 16; t2++) {
                const int t = 16 * w + t2;
                const float s = red[0][t][l] + red[1][t][l] + red[2][t][l] + red[3][t][l];
                float* yp = yb + (size_t)t2 * INNER;
                *yp = *yp + s;
            }
        }
        // ---- state update ----
        {
            const float decay = Decay[(size_t)(b * T_LEN + t0 + 63) * NH + h];
            const float* ds = DS + ((size_t)(b * T_LEN + t0 + l) * NH + h) * DH + 16 * w;
#pragma unroll
            for (int j4 = 0; j4 < 4; j4++) {
                const float4 dv = *(const float4*)(ds + 4 * j4);
                S[4 * j4 + 0] = decay * S[4 * j4 + 0] + dv.x;
                S[4 * j4 + 1] = decay * S[4 * j4 + 1] + dv.y;
                S[4 * j4 + 2] = decay * S[4 * j4 + 2] + dv.z;
                S[4 * j4 + 3] = decay * S[4 * j4 + 3] + dv.w;
            }
        }
        __syncthreads();   // red reads done before next chunk's writes
    }

    float* so = state_out + ((size_t)(b * NH + h) * DH + l) * DH + 16 * w;
#pragma unroll
    for (int j4 = 0; j4 < 4; j4++)
        *(float4*)(so + 4 * j4) = *(const float4*)&S[4 * j4];
}

// ---------------------------------------------------------------------------
extern "C" void kernel_launch(void* const* d_in, const int* in_sizes, int n_in,
                              void* d_out, int out_size, void* d_ws, size_t ws_size,
                              hipStream_t stream) {
    const float* x     = (const float*)d_in[0];
    const float* state = (const float*)d_in[1];
    const float* Wq    = (const float*)d_in[2];
    const float* Wk    = (const float*)d_in[3];
    const float* Wv    = (const float*)d_in[4];
    const float* Wa    = (const float*)d_in[5];
    const float* ba    = (const float*)d_in[6];
    const float* Wb    = (const float*)d_in[7];
    const float* bb    = (const float*)d_in[8];
    const float* Wo    = (const float*)d_in[9];

    float* ws    = (float*)d_ws;
    float* Q     = ws;                 // q -> q' (pass A)
    float* Kb    = ws + (size_t)NQ;    // k -> dS (pass A)
    float* V     = ws + 2 * (size_t)NQ;// v -> Y_intra -> Y final (pass B)
    float* Alpha = ws + 3 * (size_t)NQ;// alpha -> chunk decay at t0+63
    float* Beta  = Alpha + (size_t)NROWS * NH;

    float* out  = (float*)d_out;       // (B,T,DM)
    float* Sout = out + (size_t)NQ;    // (B,H,D,D)

    // 1) Q/K/V projections
    qkv_gemm<<<dim3(INNER / 128, NROWS / 128, 3), 256, 0, stream>>>(
        x, Wq, Wk, Wv, Q, Kb, V, INNER, DM);
    // 2) gates
    gates_kernel<<<NROWS, 256, 0, stream>>>(x, Wa, ba, Wb, bb, Alpha, Beta);
    // 3) K normalize
    knorm_kernel<<<(NROWS * NH) / 4, 256, 0, stream>>>(Kb);
    // 4) intra-chunk (parallel over 2048 chunks)
    chunk_intra<<<B_SZ * NH * NCH, 256, 0, stream>>>(Q, Kb, V, Alpha, Beta);
    // 5) inter-chunk serial scan + Y_inter add (Y finalized in V buffer)
    chunk_scan<<<B_SZ * NH, 256, 0, stream>>>(Q, Kb, V, Alpha, state, Sout);
    // 6) output projection
    sgemm128<<<dim3(DM / 128, NROWS / 128), 256, 0, stream>>>(V, Wo, out, DM, INNER);
}

// Round 3
// 911.017 us; speedup vs baseline: 3.1058x; 1.7351x over previous
//
#include <hip/hip_runtime.h>
#include <hip/hip_bf16.h>
#include <math.h>

// Problem constants
#define B_SZ   4
#define T_LEN  2048
#define DM     1024
#define NH     16
#define DH     64
#define INNER  1024          // NH*DH
#define NROWS  (B_SZ*T_LEN)  // 8192
#define NQ     (NROWS*INNER) // elements per Q/K/V/Y buffer
#define CH     64            // chunk length
#define NCH    (T_LEN/CH)    // 32 chunks

typedef __bf16 bf16x8 __attribute__((ext_vector_type(8)));
typedef __bf16 bf16x4 __attribute__((ext_vector_type(4)));
typedef float  f32x4  __attribute__((ext_vector_type(4)));
typedef __attribute__((address_space(3))) void*       lds_vp;
typedef const __attribute__((address_space(1))) void* gbl_vp;

// ---------------------------------------------------------------------------
// fp32 -> bf16 cast (x). One float4 per thread.
// ---------------------------------------------------------------------------
__global__ __launch_bounds__(256) void cast_bf16(const float* __restrict__ in,
                                                 __bf16* __restrict__ out) {
    const size_t i = (size_t)blockIdx.x * 256 + threadIdx.x;
    const float4 v = ((const float4*)in)[i];
    bf16x4 o;
    o[0] = (__bf16)v.x; o[1] = (__bf16)v.y; o[2] = (__bf16)v.z; o[3] = (__bf16)v.w;
    *(bf16x4*)(out + 4 * i) = o;
}

// ---------------------------------------------------------------------------
// Weight transpose + cast: W (K x N fp32, row-major) -> WT (N x K bf16).
// 64x64 tiles via LDS; blockIdx.z picks the matrix.
// ---------------------------------------------------------------------------
__global__ __launch_bounds__(256) void wt_cast_transpose(const float* __restrict__ Wq,
                                                         const float* __restrict__ Wk,
                                                         const float* __restrict__ Wv,
                                                         const float* __restrict__ Wo,
                                                         __bf16* __restrict__ WqT,
                                                         __bf16* __restrict__ WkT,
                                                         __bf16* __restrict__ WvT,
                                                         __bf16* __restrict__ WoT) {
    __shared__ float tile[64][65];
    const float* W;
    __bf16* WT;
    if      (blockIdx.z == 0) { W = Wq; WT = WqT; }
    else if (blockIdx.z == 1) { W = Wk; WT = WkT; }
    else if (blockIdx.z == 2) { W = Wv; WT = WvT; }
    else                      { W = Wo; WT = WoT; }

    const int k0 = blockIdx.y * 64, n0 = blockIdx.x * 64;
    const int tr  = threadIdx.x >> 4;        // 0..15
    const int tc4 = (threadIdx.x & 15) * 4;  // 0..60

#pragma unroll
    for (int r = 0; r < 4; r++) {
        const int k = tr + 16 * r;
        const float4 v = *(const float4*)(W + (size_t)(k0 + k) * DM + n0 + tc4);
        tile[k][tc4 + 0] = v.x;
        tile[k][tc4 + 1] = v.y;
        tile[k][tc4 + 2] = v.z;
        tile[k][tc4 + 3] = v.w;
    }
    __syncthreads();
#pragma unroll
    for (int r = 0; r < 4; r++) {
        const int n = tr + 16 * r;
        bf16x4 o;
#pragma unroll
        for (int j = 0; j < 4; j++) o[j] = (__bf16)tile[tc4 + j][n];
        *(bf16x4*)(WT + (size_t)(n0 + n) * DM + k0 + tc4) = o;
    }
}

// ---------------------------------------------------------------------------
// bf16 MFMA GEMM (m97 structure): C[M x N] = A[M x K] * BT[N x K]^T.
// 128x128 block tile, 4 waves, each 64x64 (4x4 of 16x16x32 MFMA), BK=32.
// Staging via global_load_lds width=16; fragment loads via ds_read_b128.
// A-frag: lane holds A[m=lane&15][k=(lane>>4)*8 + 0..7]; B-frag symmetric.
// C/D: col=lane&15, row=(lane>>4)*4+reg (verified m89/m91).
// ---------------------------------------------------------------------------
__device__ __forceinline__ void gemm_bf16_body(const __bf16* __restrict__ A,
                                               const __bf16* __restrict__ BT,
                                               float* __restrict__ C,
                                               int Ndim, int Kdim) {
    __shared__ __align__(16) __bf16 lA[128 * 32];
    __shared__ __align__(16) __bf16 lB[128 * 32];

    const int tid  = threadIdx.x;
    const int wid  = tid >> 6;
    const int lane = tid & 63;
    const int m0 = blockIdx.y * 128, n0 = blockIdx.x * 128;
    const int wm = (wid >> 1) * 64, wn = (wid & 1) * 64;

    f32x4 acc[4][4];
#pragma unroll
    for (int i = 0; i < 4; i++)
#pragma unroll
        for (int j = 0; j < 4; j++) acc[i][j] = (f32x4)0.f;

    // staging: wave w covers rows [w*32, w*32+32); 2 instrs x 16 rows;
    // lane l -> row l>>2, 8 bf16 at col (l&3)*8 (16 B / lane).
    const int srow = wid * 32 + (lane >> 2);
    const int scol = (lane & 3) * 8;
    const __bf16* gA = A  + (size_t)(m0 + srow) * Kdim + scol;
    const __bf16* gB = BT + (size_t)(n0 + srow) * Kdim + scol;

    const int qoff = (lane >> 4) * 8;   // k-offset of this lane's fragment
    const int frow = lane & 15;

    for (int k0 = 0; k0 < Kdim; k0 += 32) {
        __syncthreads();   // previous iteration's ds_reads done
#pragma unroll
        for (int i = 0; i < 2; i++) {
            __builtin_amdgcn_global_load_lds((gbl_vp)(gA + k0 + (size_t)i * 16 * Kdim),
                                             (lds_vp)(&lA[(wid * 32 + i * 16) * 32]),
                                             16, 0, 0);
            __builtin_amdgcn_global_load_lds((gbl_vp)(gB + k0 + (size_t)i * 16 * Kdim),
                                             (lds_vp)(&lB[(wid * 32 + i * 16) * 32]),
                                             16, 0, 0);
        }
        __syncthreads();   // drains vmcnt (global_load_lds) + makes LDS visible

        bf16x8 af[4], bfr[4];
#pragma unroll
        for (int t = 0; t < 4; t++) {
            af[t]  = *(const bf16x8*)&lA[(wm + t * 16 + frow) * 32 + qoff];
            bfr[t] = *(const bf16x8*)&lB[(wn + t * 16 + frow) * 32 + qoff];
        }
#pragma unroll
        for (int mi = 0; mi < 4; mi++)
#pragma unroll
            for (int nj = 0; nj < 4; nj++)
                acc[mi][nj] = __builtin_amdgcn_mfma_f32_16x16x32_bf16(
                    af[mi], bfr[nj], acc[mi][nj], 0, 0, 0);
    }

    const int cr = (lane >> 4) * 4, cc = lane & 15;
#pragma unroll
    for (int mi = 0; mi < 4; mi++) {
#pragma unroll
        for (int nj = 0; nj < 4; nj++) {
            float* Cp = C + (size_t)(m0 + wm + mi * 16 + cr) * Ndim + n0 + wn + nj * 16 + cc;
#pragma unroll
            for (int r = 0; r < 4; r++) Cp[(size_t)r * Ndim] = acc[mi][nj][r];
        }
    }
}

__global__ __launch_bounds__(256) void qkv_gemm_bf16(const __bf16* __restrict__ xb,
                                                     const __bf16* __restrict__ WqT,
                                                     const __bf16* __restrict__ WkT,
                                                     const __bf16* __restrict__ WvT,
                                                     float* __restrict__ Q,
                                                     float* __restrict__ K_,
                                                     float* __restrict__ V) {
    const __bf16* BT = (blockIdx.z == 0) ? WqT : ((blockIdx.z == 1) ? WkT : WvT);
    float*        Cm = (blockIdx.z == 0) ? Q   : ((blockIdx.z == 1) ? K_  : V);
    gemm_bf16_body(xb, BT, Cm, INNER, DM);
}

__global__ __launch_bounds__(256) void out_gemm_bf16(const __bf16* __restrict__ Yb,
                                                     const __bf16* __restrict__ WoT,
                                                     float* __restrict__ Cout) {
    gemm_bf16_body(Yb, WoT, Cout, DM, INNER);
}

// ---------------------------------------------------------------------------
// Gates: alpha = sigmoid(x@Wa + ba), beta = sigmoid(x@Wb + bb).
// ---------------------------------------------------------------------------
__global__ __launch_bounds__(256) void gates_kernel(const float* __restrict__ x,
                                                    const float* __restrict__ Wa,
                                                    const float* __restrict__ ba,
                                                    const float* __restrict__ Wb,
                                                    const float* __restrict__ bb,
                                                    float* __restrict__ Alpha,
                                                    float* __restrict__ Beta) {
    const int n = blockIdx.x;
    const int t = threadIdx.x;
    __shared__ float xs[DM];
    __shared__ float red[2][16][16];

    ((float4*)xs)[t] = ((const float4*)(x + n * DM))[t];
    __syncthreads();

    const int h = t & 15, seg = t >> 4;
    float pa = 0.f, pb = 0.f;
    const int k0 = seg * 64;
#pragma unroll 8
    for (int k = k0; k < k0 + 64; k++) {
        const float xv = xs[k];
        pa += xv * Wa[k * NH + h];
        pb += xv * Wb[k * NH + h];
    }
    red[0][seg][h] = pa;
    red[1][seg][h] = pb;
    __syncthreads();

    if (t < 32) {
        const int g = t >> 4, hh = t & 15;
        float s = 0.f;
#pragma unroll
        for (int sg = 0; sg < 16; sg++) s += red[g][sg][hh];
        s += (g == 0) ? ba[hh] : bb[hh];
        const float sig = 1.f / (1.f + __expf(-s));
        if (g == 0) Alpha[n * NH + hh] = sig;
        else        Beta[n * NH + hh]  = sig;
    }
}

// ---------------------------------------------------------------------------
// K row L2-normalize.
// ---------------------------------------------------------------------------
__global__ __launch_bounds__(256) void knorm_kernel(float* __restrict__ K) {
    const int row  = blockIdx.x * 4 + (threadIdx.x >> 6);
    const int lane = threadIdx.x & 63;
    float v = K[row * DH + lane];
    float ss = v * v;
#pragma unroll
    for (int m = 32; m >= 1; m >>= 1) ss += __shfl_xor(ss, m, 64);
    const float scale = 1.f / fmaxf(sqrtf(ss), 1e-12f);
    K[row * DH + lane] = v * scale;
}

// ---------------------------------------------------------------------------
// Pass A: per-(b,h,chunk) intra-chunk work. 2048 blocks x 256 threads.
// (unchanged from round 2 — see comments there)
// ---------------------------------------------------------------------------
__global__ __launch_bounds__(256) void chunk_intra(float* __restrict__ Q,
                                                   float* __restrict__ K,
                                                   float* __restrict__ V,
                                                   float* __restrict__ Alpha,
                                                   const float* __restrict__ Beta) {
    __shared__ float sQ[64][68];    // later reused to hold A
    __shared__ float sK[64][68];
    __shared__ float sKT[64][68];
    __shared__ float sV[64][68];
    __shared__ __align__(16) float sla[64];
    __shared__ __align__(16) float sexp[64];
    __shared__ __align__(16) float sb[64];
    __shared__ __align__(16) float swd[64];

    const int blk = blockIdx.x;
    const int c = blk & 31, h = (blk >> 5) & 15, b = blk >> 9;
    const int t0 = c * CH;
    const int tid = threadIdx.x;
    const int ty = tid >> 4, tx = tid & 15;
    const size_t rowbase = ((size_t)(b * T_LEN + t0) * NH + h) * DH;

#pragma unroll
    for (int r = 0; r < 4; r++) {
        const int row = ty + 16 * r;
        const int col = tx * 4;
        const size_t g = rowbase + (size_t)row * INNER + col;
        const float4 qv = *(const float4*)(Q + g);
        const float4 kv = *(const float4*)(K + g);
        const float4 vv = *(const float4*)(V + g);
        *(float4*)&sQ[row][col] = qv;
        *(float4*)&sK[row][col] = kv;
        *(float4*)&sV[row][col] = vv;
        sKT[col + 0][row] = kv.x;
        sKT[col + 1][row] = kv.y;
        sKT[col + 2][row] = kv.z;
        sKT[col + 3][row] = kv.w;
    }
    if (tid < 64) {
        const int t = tid;
        const size_t ga = (size_t)(b * T_LEN + t0 + t) * NH + h;
        const float a  = Alpha[ga];
        const float bt = Beta[ga];
        float x = logf(a);
#pragma unroll
        for (int off = 1; off < 64; off <<= 1) {
            const float y = __shfl_up(x, off, 64);
            if (t >= off) x += y;
        }
        const float la63 = __shfl(x, 63, 64);
        sla[t]  = x;
        sexp[t] = expf(x);
        sb[t]   = bt;
        swd[t]  = bt * expf(la63 - x);
        if (t == 63) Alpha[ga] = expf(la63);   // chunk total decay for pass B
    }
    __syncthreads();

    const int tt0 = ty * 4, ss0 = tx * 4;

    float g4[4][4];
#pragma unroll
    for (int i = 0; i < 4; i++)
#pragma unroll
        for (int j = 0; j < 4; j++) g4[i][j] = 0.f;
    for (int d = 0; d < 64; d += 4) {
        float qa[4][4], ka[4][4];
#pragma unroll
        for (int i = 0; i < 4; i++) *(float4*)&qa[i][0] = *(const float4*)&sQ[tt0 + i][d];
#pragma unroll
        for (int k = 0; k < 4; k++) *(float4*)&ka[k][0] = *(const float4*)&sKT[d + k][ss0];
#pragma unroll
        for (int i = 0; i < 4; i++)
#pragma unroll
            for (int k = 0; k < 4; k++)
#pragma unroll
                for (int j = 0; j < 4; j++) g4[i][j] += qa[i][k] * ka[k][j];
    }

#pragma unroll
    for (int r = 0; r < 4; r++) {
        const int row = ty + 16 * r;
        const int col = tx * 4;
        float4 qv = *(const float4*)&sQ[row][col];
        const float e = sexp[row];
        qv.x *= e; qv.y *= e; qv.z *= e; qv.w *= e;
        *(float4*)(Q + rowbase + (size_t)row * INNER + col) = qv;
    }
    __syncthreads();

    {
#pragma unroll
        for (int i = 0; i < 4; i++) {
            float av[4];
            const int t = tt0 + i;
#pragma unroll
            for (int j = 0; j < 4; j++) {
                const int s = ss0 + j;
                av[j] = (s <= t) ? expf(sla[t] - sla[s]) * sb[s] * g4[i][j] : 0.f;
            }
            *(float4*)&sQ[t][ss0] = *(float4*)&av[0];
        }
    }
    __syncthreads();

    {
        float y4[4][4];
#pragma unroll
        for (int i = 0; i < 4; i++)
#pragma unroll
            for (int j = 0; j < 4; j++) y4[i][j] = 0.f;
        for (int s = 0; s < 64; s += 4) {
            float aa[4][4], vv[4][4];
#pragma unroll
            for (int i = 0; i < 4; i++) *(float4*)&aa[i][0] = *(const float4*)&sQ[tt0 + i][s];
#pragma unroll
            for (int k = 0; k < 4; k++) *(float4*)&vv[k][0] = *(const float4*)&sV[s + k][ss0];
#pragma unroll
            for (int i = 0; i < 4; i++)
#pragma unroll
                for (int k = 0; k < 4; k++)
#pragma unroll
                    for (int j = 0; j < 4; j++) y4[i][j] += aa[i][k] * vv[k][j];
        }
#pragma unroll
        for (int i = 0; i < 4; i++)
            *(float4*)(V + rowbase + (size_t)(tt0 + i) * INNER + ss0) = *(float4*)&y4[i][0];
    }

    {
        float d4[4][4];
#pragma unroll
        for (int i = 0; i < 4; i++)
#pragma unroll
            for (int j = 0; j < 4; j++) d4[i][j] = 0.f;
        for (int s = 0; s < 64; s += 4) {
            float vv[4][4], kk[4][4], wv[4];
            *(float4*)&wv[0] = *(const float4*)&swd[s];
#pragma unroll
            for (int k = 0; k < 4; k++) *(float4*)&vv[k][0] = *(const float4*)&sV[s + k][tt0];
#pragma unroll
            for (int k = 0; k < 4; k++) *(float4*)&kk[k][0] = *(const float4*)&sK[s + k][ss0];
#pragma unroll
            for (int k = 0; k < 4; k++) {
#pragma unroll
                for (int i = 0; i < 4; i++) {
                    const float wvi = wv[k] * vv[k][i];
#pragma unroll
                    for (int j = 0; j < 4; j++) d4[i][j] += wvi * kk[k][j];
                }
            }
        }
#pragma unroll
        for (int i = 0; i < 4; i++)
            *(float4*)(K + rowbase + (size_t)(tt0 + i) * INNER + ss0) = *(float4*)&d4[i][0];
    }
}

// ---------------------------------------------------------------------------
// Pass B: serial over 32 chunks per (b,h). 64 blocks x 256 threads.
// Output Y now written as bf16 (for the bf16 output projection):
//   Yb[t] = (bf16)( Y_intra[t] (fp32, from V buffer) + Y_inter[t] ).
// ---------------------------------------------------------------------------
__global__ __launch_bounds__(256) void chunk_scan(const float* __restrict__ Qp,
                                                  const float* __restrict__ DS,
                                                  const float* __restrict__ Yin,
                                                  __bf16* __restrict__ Yb,
                                                  const float* __restrict__ Decay,
                                                  const float* __restrict__ state_in,
                                                  float* __restrict__ state_out) {
    __shared__ float red[4][64][64];

    const int blk = blockIdx.x;          // (b,h)
    const int b = blk >> 4, h = blk & 15;
    const int tid = threadIdx.x;
    const int w = __builtin_amdgcn_readfirstlane(tid >> 6);
    const int l = tid & 63;

    float S[16];
    {
        const float* st = state_in + ((size_t)(b * NH + h) * DH + l) * DH + 16 * w;
#pragma unroll
        for (int j4 = 0; j4 < 4; j4++)
            *(float4*)&S[4 * j4] = *(const float4*)(st + 4 * j4);
    }

    for (int c = 0; c < NCH; c++) {
        const int t0 = c * CH;
        const float* qbase = Qp + ((size_t)(b * T_LEN + t0) * NH + h) * DH + 16 * w;
#pragma unroll 4
        for (int t = 0; t < 64; t++) {
            const float* qp = qbase + (size_t)t * INNER;
            const float4 q0 = *(const float4*)(qp + 0);
            const float4 q1 = *(const float4*)(qp + 4);
            const float4 q2 = *(const float4*)(qp + 8);
            const float4 q3 = *(const float4*)(qp + 12);
            float p = q0.x * S[0]  + q0.y * S[1]  + q0.z * S[2]  + q0.w * S[3]
                    + q1.x * S[4]  + q1.y * S[5]  + q1.z * S[6]  + q1.w * S[7]
                    + q2.x * S[8]  + q2.y * S[9]  + q2.z * S[10] + q2.w * S[11]
                    + q3.x * S[12] + q3.y * S[13] + q3.z * S[14] + q3.w * S[15];
            red[w][t][l] = p;
        }
        __syncthreads();
        {
            const size_t ybase = ((size_t)(b * T_LEN + t0 + 16 * w) * NH + h) * DH + l;
#pragma unroll 4
            for (int t2 = 0; t2 < 16; t2++) {
                const int t = 16 * w + t2;
                const float s = red[0][t][l] + red[1][t][l] + red[2][t][l] + red[3][t][l];
                const size_t g = ybase + (size_t)t2 * INNER;
                Yb[g] = (__bf16)(s + Yin[g]);
            }
        }
        {
            const float decay = Decay[(size_t)(b * T_LEN + t0 + 63) * NH + h];
            const float* ds = DS + ((size_t)(b * T_LEN + t0 + l) * NH + h) * DH + 16 * w;
#pragma unroll
            for (int j4 = 0; j4 < 4; j4++) {
                const float4 dv = *(const float4*)(ds + 4 * j4);
                S[4 * j4 + 0] = decay * S[4 * j4 + 0] + dv.x;
                S[4 * j4 + 1] = decay * S[4 * j4 + 1] + dv.y;
                S[4 * j4 + 2] = decay * S[4 * j4 + 2] + dv.z;
                S[4 * j4 + 3] = decay * S[4 * j4 + 3] + dv.w;
            }
        }
        __syncthreads();
    }

    float* so = state_out + ((size_t)(b * NH + h) * DH + l) * DH + 16 * w;
#pragma unroll
    for (int j4 = 0; j4 < 4; j4++)
        *(float4*)(so + 4 * j4) = *(const float4*)&S[4 * j4];
}

// ---------------------------------------------------------------------------
extern "C" void kernel_launch(void* const* d_in, const int* in_sizes, int n_in,
                              void* d_out, int out_size, void* d_ws, size_t ws_size,
                              hipStream_t stream) {
    const float* x     = (const float*)d_in[0];
    const float* state = (const float*)d_in[1];
    const float* Wq    = (const float*)d_in[2];
    const float* Wk    = (const float*)d_in[3];
    const float* Wv    = (const float*)d_in[4];
    const float* Wa    = (const float*)d_in[5];
    const float* ba    = (const float*)d_in[6];
    const float* Wb    = (const float*)d_in[7];
    const float* bb    = (const float*)d_in[8];
    const float* Wo    = (const float*)d_in[9];

    float* ws    = (float*)d_ws;
    float* Q     = ws;                          // q -> q' (pass A)
    float* Kb    = ws + (size_t)NQ;             // k -> dS (pass A)
    float* V     = ws + 2 * (size_t)NQ;         // v -> Y_intra (pass A)
    float* Alpha = ws + 3 * (size_t)NQ;         // alpha -> chunk decay at t0+63
    float* Beta  = Alpha + (size_t)NROWS * NH;
    __bf16* xb   = (__bf16*)(Beta + (size_t)NROWS * NH);  // NQ bf16
    __bf16* Yb   = xb;                          // reuse: xb dead after qkv gemm
    __bf16* WqT  = xb + (size_t)NQ;
    __bf16* WkT  = WqT + (size_t)DM * INNER;
    __bf16* WvT  = WkT + (size_t)DM * INNER;
    __bf16* WoT  = WvT + (size_t)DM * INNER;

    float* out  = (float*)d_out;                // (B,T,DM)
    float* Sout = out + (size_t)NQ;             // (B,H,D,D)

    // 0) casts
    cast_bf16<<<NQ / 1024, 256, 0, stream>>>(x, xb);
    wt_cast_transpose<<<dim3(16, 16, 4), 256, 0, stream>>>(Wq, Wk, Wv, Wo,
                                                           WqT, WkT, WvT, WoT);
    // 1) Q/K/V projections (bf16 MFMA)
    qkv_gemm_bf16<<<dim3(INNER / 128, NROWS / 128, 3), 256, 0, stream>>>(
        xb, WqT, WkT, WvT, Q, Kb, V);
    // 2) gates
    gates_kernel<<<NROWS, 256, 0, stream>>>(x, Wa, ba, Wb, bb, Alpha, Beta);
    // 3) K normalize
    knorm_kernel<<<(NROWS * NH) / 4, 256, 0, stream>>>(Kb);
    // 4) intra-chunk (parallel over 2048 chunks)
    chunk_intra<<<B_SZ * NH * NCH, 256, 0, stream>>>(Q, Kb, V, Alpha, Beta);
    // 5) inter-chunk serial scan; writes final Y as bf16 into Yb
    chunk_scan<<<B_SZ * NH, 256, 0, stream>>>(Q, Kb, V, Yb, Alpha, state, Sout);
    // 6) output projection (bf16 MFMA)
    out_gemm_bf16<<<dim3(DM / 128, NROWS / 128), 256, 0, stream>>>(Yb, WoT, out);
}

// Round 4
// 547.850 us; speedup vs baseline: 5.1646x; 1.6629x over previous
//
#include <hip/hip_runtime.h>
#include <hip/hip_bf16.h>
#include <math.h>

// Problem constants
#define B_SZ   4
#define T_LEN  2048
#define DM     1024
#define NH     16
#define DH     64
#define INNER  1024          // NH*DH
#define NROWS  (B_SZ*T_LEN)  // 8192
#define NQ     (NROWS*INNER) // elements per Q/K/V/Y buffer
#define CH     64            // chunk length
#define NCH    (T_LEN/CH)    // 32 chunks

typedef __bf16 bf16x8 __attribute__((ext_vector_type(8)));
typedef __bf16 bf16x4 __attribute__((ext_vector_type(4)));
typedef float  f32x4  __attribute__((ext_vector_type(4)));
typedef __attribute__((address_space(3))) void*       lds_vp;
typedef const __attribute__((address_space(1))) void* gbl_vp;

// ---------------------------------------------------------------------------
// fp32 -> bf16 cast (x). One float4 per thread.
// ---------------------------------------------------------------------------
__global__ __launch_bounds__(256) void cast_bf16(const float* __restrict__ in,
                                                 __bf16* __restrict__ out) {
    const size_t i = (size_t)blockIdx.x * 256 + threadIdx.x;
    const float4 v = ((const float4*)in)[i];
    bf16x4 o;
    o[0] = (__bf16)v.x; o[1] = (__bf16)v.y; o[2] = (__bf16)v.z; o[3] = (__bf16)v.w;
    *(bf16x4*)(out + 4 * i) = o;
}

// ---------------------------------------------------------------------------
// Weight transpose + cast: W (K x N fp32, row-major) -> WT (N x K bf16).
// ---------------------------------------------------------------------------
__global__ __launch_bounds__(256) void wt_cast_transpose(const float* __restrict__ Wq,
                                                         const float* __restrict__ Wk,
                                                         const float* __restrict__ Wv,
                                                         const float* __restrict__ Wo,
                                                         __bf16* __restrict__ WqT,
                                                         __bf16* __restrict__ WkT,
                                                         __bf16* __restrict__ WvT,
                                                         __bf16* __restrict__ WoT) {
    __shared__ float tile[64][65];
    const float* W;
    __bf16* WT;
    if      (blockIdx.z == 0) { W = Wq; WT = WqT; }
    else if (blockIdx.z == 1) { W = Wk; WT = WkT; }
    else if (blockIdx.z == 2) { W = Wv; WT = WvT; }
    else                      { W = Wo; WT = WoT; }

    const int k0 = blockIdx.y * 64, n0 = blockIdx.x * 64;
    const int tr  = threadIdx.x >> 4;        // 0..15
    const int tc4 = (threadIdx.x & 15) * 4;  // 0..60

#pragma unroll
    for (int r = 0; r < 4; r++) {
        const int k = tr + 16 * r;
        const float4 v = *(const float4*)(W + (size_t)(k0 + k) * DM + n0 + tc4);
        tile[k][tc4 + 0] = v.x;
        tile[k][tc4 + 1] = v.y;
        tile[k][tc4 + 2] = v.z;
        tile[k][tc4 + 3] = v.w;
    }
    __syncthreads();
#pragma unroll
    for (int r = 0; r < 4; r++) {
        const int n = tr + 16 * r;
        bf16x4 o;
#pragma unroll
        for (int j = 0; j < 4; j++) o[j] = (__bf16)tile[tc4 + j][n];
        *(bf16x4*)(WT + (size_t)(n0 + n) * DM + k0 + tc4) = o;
    }
}

// ---------------------------------------------------------------------------
// bf16 MFMA GEMM (m97 structure): C[M x N] = A[M x K] * BT[N x K]^T.
// ---------------------------------------------------------------------------
__device__ __forceinline__ void gemm_bf16_body(const __bf16* __restrict__ A,
                                               const __bf16* __restrict__ BT,
                                               float* __restrict__ C,
                                               int Ndim, int Kdim) {
    __shared__ __align__(16) __bf16 lA[128 * 32];
    __shared__ __align__(16) __bf16 lB[128 * 32];

    const int tid  = threadIdx.x;
    const int wid  = tid >> 6;
    const int lane = tid & 63;
    const int m0 = blockIdx.y * 128, n0 = blockIdx.x * 128;
    const int wm = (wid >> 1) * 64, wn = (wid & 1) * 64;

    f32x4 acc[4][4];
#pragma unroll
    for (int i = 0; i < 4; i++)
#pragma unroll
        for (int j = 0; j < 4; j++) acc[i][j] = (f32x4)0.f;

    const int srow = wid * 32 + (lane >> 2);
    const int scol = (lane & 3) * 8;
    const __bf16* gA = A  + (size_t)(m0 + srow) * Kdim + scol;
    const __bf16* gB = BT + (size_t)(n0 + srow) * Kdim + scol;

    const int qoff = (lane >> 4) * 8;
    const int frow = lane & 15;

    for (int k0 = 0; k0 < Kdim; k0 += 32) {
        __syncthreads();
#pragma unroll
        for (int i = 0; i < 2; i++) {
            __builtin_amdgcn_global_load_lds((gbl_vp)(gA + k0 + (size_t)i * 16 * Kdim),
                                             (lds_vp)(&lA[(wid * 32 + i * 16) * 32]),
                                             16, 0, 0);
            __builtin_amdgcn_global_load_lds((gbl_vp)(gB + k0 + (size_t)i * 16 * Kdim),
                                             (lds_vp)(&lB[(wid * 32 + i * 16) * 32]),
                                             16, 0, 0);
        }
        __syncthreads();

        bf16x8 af[4], bfr[4];
#pragma unroll
        for (int t = 0; t < 4; t++) {
            af[t]  = *(const bf16x8*)&lA[(wm + t * 16 + frow) * 32 + qoff];
            bfr[t] = *(const bf16x8*)&lB[(wn + t * 16 + frow) * 32 + qoff];
        }
#pragma unroll
        for (int mi = 0; mi < 4; mi++)
#pragma unroll
            for (int nj = 0; nj < 4; nj++)
                acc[mi][nj] = __builtin_amdgcn_mfma_f32_16x16x32_bf16(
                    af[mi], bfr[nj], acc[mi][nj], 0, 0, 0);
    }

    const int cr = (lane >> 4) * 4, cc = lane & 15;
#pragma unroll
    for (int mi = 0; mi < 4; mi++) {
#pragma unroll
        for (int nj = 0; nj < 4; nj++) {
            float* Cp = C + (size_t)(m0 + wm + mi * 16 + cr) * Ndim + n0 + wn + nj * 16 + cc;
#pragma unroll
            for (int r = 0; r < 4; r++) Cp[(size_t)r * Ndim] = acc[mi][nj][r];
        }
    }
}

__global__ __launch_bounds__(256) void qkv_gemm_bf16(const __bf16* __restrict__ xb,
                                                     const __bf16* __restrict__ WqT,
                                                     const __bf16* __restrict__ WkT,
                                                     const __bf16* __restrict__ WvT,
                                                     float* __restrict__ Q,
                                                     float* __restrict__ K_,
                                                     float* __restrict__ V) {
    const __bf16* BT = (blockIdx.z == 0) ? WqT : ((blockIdx.z == 1) ? WkT : WvT);
    float*        Cm = (blockIdx.z == 0) ? Q   : ((blockIdx.z == 1) ? K_  : V);
    gemm_bf16_body(xb, BT, Cm, INNER, DM);
}

__global__ __launch_bounds__(256) void out_gemm_bf16(const __bf16* __restrict__ Yb,
                                                     const __bf16* __restrict__ WoT,
                                                     float* __restrict__ Cout) {
    gemm_bf16_body(Yb, WoT, Cout, DM, INNER);
}

// ---------------------------------------------------------------------------
// Gates: alpha = sigmoid(x@Wa + ba), beta = sigmoid(x@Wb + bb).
// ---------------------------------------------------------------------------
__global__ __launch_bounds__(256) void gates_kernel(const float* __restrict__ x,
                                                    const float* __restrict__ Wa,
                                                    const float* __restrict__ ba,
                                                    const float* __restrict__ Wb,
                                                    const float* __restrict__ bb,
                                                    float* __restrict__ Alpha,
                                                    float* __restrict__ Beta) {
    const int n = blockIdx.x;
    const int t = threadIdx.x;
    __shared__ float xs[DM];
    __shared__ float red[2][16][16];

    ((float4*)xs)[t] = ((const float4*)(x + n * DM))[t];
    __syncthreads();

    const int h = t & 15, seg = t >> 4;
    float pa = 0.f, pb = 0.f;
    const int k0 = seg * 64;
#pragma unroll 8
    for (int k = k0; k < k0 + 64; k++) {
        const float xv = xs[k];
        pa += xv * Wa[k * NH + h];
        pb += xv * Wb[k * NH + h];
    }
    red[0][seg][h] = pa;
    red[1][seg][h] = pb;
    __syncthreads();

    if (t < 32) {
        const int g = t >> 4, hh = t & 15;
        float s = 0.f;
#pragma unroll
        for (int sg = 0; sg < 16; sg++) s += red[g][sg][hh];
        s += (g == 0) ? ba[hh] : bb[hh];
        const float sig = 1.f / (1.f + __expf(-s));
        if (g == 0) Alpha[n * NH + hh] = sig;
        else        Beta[n * NH + hh]  = sig;
    }
}

// ---------------------------------------------------------------------------
// K row L2-normalize.
// ---------------------------------------------------------------------------
__global__ __launch_bounds__(256) void knorm_kernel(float* __restrict__ K) {
    const int row  = blockIdx.x * 4 + (threadIdx.x >> 6);
    const int lane = threadIdx.x & 63;
    float v = K[row * DH + lane];
    float ss = v * v;
#pragma unroll
    for (int m = 32; m >= 1; m >>= 1) ss += __shfl_xor(ss, m, 64);
    const float scale = 1.f / fmaxf(sqrtf(ss), 1e-12f);
    K[row * DH + lane] = v * scale;
}

// ---------------------------------------------------------------------------
// Pass A: per-(b,h,chunk) intra-chunk work. 2048 blocks x 256 threads.
// ---------------------------------------------------------------------------
__global__ __launch_bounds__(256) void chunk_intra(float* __restrict__ Q,
                                                   float* __restrict__ K,
                                                   float* __restrict__ V,
                                                   float* __restrict__ Alpha,
                                                   const float* __restrict__ Beta) {
    __shared__ float sQ[64][68];    // later reused to hold A
    __shared__ float sK[64][68];
    __shared__ float sKT[64][68];
    __shared__ float sV[64][68];
    __shared__ __align__(16) float sla[64];
    __shared__ __align__(16) float sexp[64];
    __shared__ __align__(16) float sb[64];
    __shared__ __align__(16) float swd[64];

    const int blk = blockIdx.x;
    const int c = blk & 31, h = (blk >> 5) & 15, b = blk >> 9;
    const int t0 = c * CH;
    const int tid = threadIdx.x;
    const int ty = tid >> 4, tx = tid & 15;
    const size_t rowbase = ((size_t)(b * T_LEN + t0) * NH + h) * DH;

#pragma unroll
    for (int r = 0; r < 4; r++) {
        const int row = ty + 16 * r;
        const int col = tx * 4;
        const size_t g = rowbase + (size_t)row * INNER + col;
        const float4 qv = *(const float4*)(Q + g);
        const float4 kv = *(const float4*)(K + g);
        const float4 vv = *(const float4*)(V + g);
        *(float4*)&sQ[row][col] = qv;
        *(float4*)&sK[row][col] = kv;
        *(float4*)&sV[row][col] = vv;
        sKT[col + 0][row] = kv.x;
        sKT[col + 1][row] = kv.y;
        sKT[col + 2][row] = kv.z;
        sKT[col + 3][row] = kv.w;
    }
    if (tid < 64) {
        const int t = tid;
        const size_t ga = (size_t)(b * T_LEN + t0 + t) * NH + h;
        const float a  = Alpha[ga];
        const float bt = Beta[ga];
        float x = logf(a);
#pragma unroll
        for (int off = 1; off < 64; off <<= 1) {
            const float y = __shfl_up(x, off, 64);
            if (t >= off) x += y;
        }
        const float la63 = __shfl(x, 63, 64);
        sla[t]  = x;
        sexp[t] = expf(x);
        sb[t]   = bt;
        swd[t]  = bt * expf(la63 - x);
        if (t == 63) Alpha[ga] = expf(la63);   // chunk total decay
    }
    __syncthreads();

    const int tt0 = ty * 4, ss0 = tx * 4;

    float g4[4][4];
#pragma unroll
    for (int i = 0; i < 4; i++)
#pragma unroll
        for (int j = 0; j < 4; j++) g4[i][j] = 0.f;
    for (int d = 0; d < 64; d += 4) {
        float qa[4][4], ka[4][4];
#pragma unroll
        for (int i = 0; i < 4; i++) *(float4*)&qa[i][0] = *(const float4*)&sQ[tt0 + i][d];
#pragma unroll
        for (int k = 0; k < 4; k++) *(float4*)&ka[k][0] = *(const float4*)&sKT[d + k][ss0];
#pragma unroll
        for (int i = 0; i < 4; i++)
#pragma unroll
            for (int k = 0; k < 4; k++)
#pragma unroll
                for (int j = 0; j < 4; j++) g4[i][j] += qa[i][k] * ka[k][j];
    }

#pragma unroll
    for (int r = 0; r < 4; r++) {
        const int row = ty + 16 * r;
        const int col = tx * 4;
        float4 qv = *(const float4*)&sQ[row][col];
        const float e = sexp[row];
        qv.x *= e; qv.y *= e; qv.z *= e; qv.w *= e;
        *(float4*)(Q + rowbase + (size_t)row * INNER + col) = qv;
    }
    __syncthreads();

    {
#pragma unroll
        for (int i = 0; i < 4; i++) {
            float av[4];
            const int t = tt0 + i;
#pragma unroll
            for (int j = 0; j < 4; j++) {
                const int s = ss0 + j;
                av[j] = (s <= t) ? expf(sla[t] - sla[s]) * sb[s] * g4[i][j] : 0.f;
            }
            *(float4*)&sQ[t][ss0] = *(float4*)&av[0];
        }
    }
    __syncthreads();

    {
        float y4[4][4];
#pragma unroll
        for (int i = 0; i < 4; i++)
#pragma unroll
            for (int j = 0; j < 4; j++) y4[i][j] = 0.f;
        for (int s = 0; s < 64; s += 4) {
            float aa[4][4], vv[4][4];
#pragma unroll
            for (int i = 0; i < 4; i++) *(float4*)&aa[i][0] = *(const float4*)&sQ[tt0 + i][s];
#pragma unroll
            for (int k = 0; k < 4; k++) *(float4*)&vv[k][0] = *(const float4*)&sV[s + k][ss0];
#pragma unroll
            for (int i = 0; i < 4; i++)
#pragma unroll
                for (int k = 0; k < 4; k++)
#pragma unroll
                    for (int j = 0; j < 4; j++) y4[i][j] += aa[i][k] * vv[k][j];
        }
#pragma unroll
        for (int i = 0; i < 4; i++)
            *(float4*)(V + rowbase + (size_t)(tt0 + i) * INNER + ss0) = *(float4*)&y4[i][0];
    }

    {
        float d4[4][4];
#pragma unroll
        for (int i = 0; i < 4; i++)
#pragma unroll
            for (int j = 0; j < 4; j++) d4[i][j] = 0.f;
        for (int s = 0; s < 64; s += 4) {
            float vv[4][4], kk[4][4], wv[4];
            *(float4*)&wv[0] = *(const float4*)&swd[s];
#pragma unroll
            for (int k = 0; k < 4; k++) *(float4*)&vv[k][0] = *(const float4*)&sV[s + k][tt0];
#pragma unroll
            for (int k = 0; k < 4; k++) *(float4*)&kk[k][0] = *(const float4*)&sK[s + k][ss0];
#pragma unroll
            for (int k = 0; k < 4; k++) {
#pragma unroll
                for (int i = 0; i < 4; i++) {
                    const float wvi = wv[k] * vv[k][i];
#pragma unroll
                    for (int j = 0; j < 4; j++) d4[i][j] += wvi * kk[k][j];
                }
            }
        }
#pragma unroll
        for (int i = 0; i < 4; i++)
            *(float4*)(K + rowbase + (size_t)(tt0 + i) * INNER + ss0) = *(float4*)&d4[i][0];
    }
}

// ---------------------------------------------------------------------------
// Pass B1 (serial, tiny): S_{c+1} = d_c * S_c + dS_c over 32 chunks per
// (b,h).  Writes each PRE-update state S_c in-place over the dS slot it just
// consumed (one-to-one thread<->slot mapping, no hazard).  64 blocks x 256
// threads; thread (w=tid>>6, l=tid&63) owns S[i=l][j=16w..16w+16).
// ---------------------------------------------------------------------------
__global__ __launch_bounds__(256) void chunk_state(float* __restrict__ DS,
                                                   const float* __restrict__ Decay,
                                                   const float* __restrict__ state_in,
                                                   float* __restrict__ state_out) {
    const int blk = blockIdx.x;          // (b,h)
    const int b = blk >> 4, h = blk & 15;
    const int tid = threadIdx.x;
    const int w = tid >> 6;
    const int l = tid & 63;

    float S[16];
    {
        const float* st = state_in + ((size_t)(b * NH + h) * DH + l) * DH + 16 * w;
#pragma unroll
        for (int j4 = 0; j4 < 4; j4++)
            *(float4*)&S[4 * j4] = *(const float4*)(st + 4 * j4);
    }

    for (int c = 0; c < NCH; c++) {
        const int t0 = c * CH;
        const float decay = Decay[(size_t)(b * T_LEN + t0 + 63) * NH + h];
        float* ds = DS + ((size_t)(b * T_LEN + t0 + l) * NH + h) * DH + 16 * w;
        float4 dv[4];
#pragma unroll
        for (int j4 = 0; j4 < 4; j4++) dv[j4] = *(const float4*)(ds + 4 * j4);
        // store pre-update chunk-initial state S_c over the dS slot
#pragma unroll
        for (int j4 = 0; j4 < 4; j4++) *(float4*)(ds + 4 * j4) = *(const float4*)&S[4 * j4];
#pragma unroll
        for (int j4 = 0; j4 < 4; j4++) {
            S[4 * j4 + 0] = decay * S[4 * j4 + 0] + dv[j4].x;
            S[4 * j4 + 1] = decay * S[4 * j4 + 1] + dv[j4].y;
            S[4 * j4 + 2] = decay * S[4 * j4 + 2] + dv[j4].z;
            S[4 * j4 + 3] = decay * S[4 * j4 + 3] + dv[j4].w;
        }
    }

    float* so = state_out + ((size_t)(b * NH + h) * DH + l) * DH + 16 * w;
#pragma unroll
    for (int j4 = 0; j4 < 4; j4++)
        *(float4*)(so + 4 * j4) = *(const float4*)&S[4 * j4];
}

// ---------------------------------------------------------------------------
// Pass B2 (parallel): per (b,h,c) compute Y_inter = Q' Sc^T, add Y_intra,
// write bf16 Yb.  2048 blocks x 256 threads, same tiling as chunk_intra's G.
//   Y[t][i] = Yin[t][i] + sum_j Qp[t][j] * Sc[i][j]
// ---------------------------------------------------------------------------
__global__ __launch_bounds__(256) void y_finalize(const float* __restrict__ Qp,
                                                  const float* __restrict__ Sc,
                                                  const float* __restrict__ Yin,
                                                  __bf16* __restrict__ Yb) {
    __shared__ float sQ[64][68];
    __shared__ float sST[64][68];   // sST[j][i] = Sc[i][j]

    const int blk = blockIdx.x;
    const int c = blk & 31, h = (blk >> 5) & 15, b = blk >> 9;
    const int t0 = c * CH;
    const int tid = threadIdx.x;
    const int ty = tid >> 4, tx = tid & 15;
    const size_t rowbase = ((size_t)(b * T_LEN + t0) * NH + h) * DH;

#pragma unroll
    for (int r = 0; r < 4; r++) {
        const int row = ty + 16 * r;
        const int col = tx * 4;
        const size_t g = rowbase + (size_t)row * INNER + col;
        const float4 qv = *(const float4*)(Qp + g);
        const float4 sv = *(const float4*)(Sc + g);
        *(float4*)&sQ[row][col] = qv;
        sST[col + 0][row] = sv.x;
        sST[col + 1][row] = sv.y;
        sST[col + 2][row] = sv.z;
        sST[col + 3][row] = sv.w;
    }
    __syncthreads();

    const int tt0 = ty * 4, ss0 = tx * 4;
    float y4[4][4];
#pragma unroll
    for (int i = 0; i < 4; i++)
#pragma unroll
        for (int j = 0; j < 4; j++) y4[i][j] = 0.f;
    for (int d = 0; d < 64; d += 4) {
        float qa[4][4], sa[4][4];
#pragma unroll
        for (int i = 0; i < 4; i++) *(float4*)&qa[i][0] = *(const float4*)&sQ[tt0 + i][d];
#pragma unroll
        for (int k = 0; k < 4; k++) *(float4*)&sa[k][0] = *(const float4*)&sST[d + k][ss0];
#pragma unroll
        for (int i = 0; i < 4; i++)
#pragma unroll
            for (int k = 0; k < 4; k++)
#pragma unroll
                for (int j = 0; j < 4; j++) y4[i][j] += qa[i][k] * sa[k][j];
    }

#pragma unroll
    for (int i = 0; i < 4; i++) {
        const size_t g = rowbase + (size_t)(tt0 + i) * INNER + ss0;
        const float4 yi = *(const float4*)(Yin + g);
        bf16x4 o;
        o[0] = (__bf16)(y4[i][0] + yi.x);
        o[1] = (__bf16)(y4[i][1] + yi.y);
        o[2] = (__bf16)(y4[i][2] + yi.z);
        o[3] = (__bf16)(y4[i][3] + yi.w);
        *(bf16x4*)(Yb + g) = o;
    }
}

// ---------------------------------------------------------------------------
extern "C" void kernel_launch(void* const* d_in, const int* in_sizes, int n_in,
                              void* d_out, int out_size, void* d_ws, size_t ws_size,
                              hipStream_t stream) {
    const float* x     = (const float*)d_in[0];
    const float* state = (const float*)d_in[1];
    const float* Wq    = (const float*)d_in[2];
    const float* Wk    = (const float*)d_in[3];
    const float* Wv    = (const float*)d_in[4];
    const float* Wa    = (const float*)d_in[5];
    const float* ba    = (const float*)d_in[6];
    const float* Wb    = (const float*)d_in[7];
    const float* bb    = (const float*)d_in[8];
    const float* Wo    = (const float*)d_in[9];

    float* ws    = (float*)d_ws;
    float* Q     = ws;                          // q -> q' (pass A)
    float* Kb    = ws + (size_t)NQ;             // k -> dS (A) -> Sc (B1)
    float* V     = ws + 2 * (size_t)NQ;         // v -> Y_intra (pass A)
    float* Alpha = ws + 3 * (size_t)NQ;         // alpha -> chunk decay at t0+63
    float* Beta  = Alpha + (size_t)NROWS * NH;
    __bf16* xb   = (__bf16*)(Beta + (size_t)NROWS * NH);  // NQ bf16
    __bf16* Yb   = xb;                          // reuse: xb dead after qkv gemm
    __bf16* WqT  = xb + (size_t)NQ;
    __bf16* WkT  = WqT + (size_t)DM * INNER;
    __bf16* WvT  = WkT + (size_t)DM * INNER;
    __bf16* WoT  = WvT + (size_t)DM * INNER;

    float* out  = (float*)d_out;                // (B,T,DM)
    float* Sout = out + (size_t)NQ;             // (B,H,D,D)

    // 0) casts
    cast_bf16<<<NQ / 1024, 256, 0, stream>>>(x, xb);
    wt_cast_transpose<<<dim3(16, 16, 4), 256, 0, stream>>>(Wq, Wk, Wv, Wo,
                                                           WqT, WkT, WvT, WoT);
    // 1) Q/K/V projections (bf16 MFMA)
    qkv_gemm_bf16<<<dim3(INNER / 128, NROWS / 128, 3), 256, 0, stream>>>(
        xb, WqT, WkT, WvT, Q, Kb, V);
    // 2) gates
    gates_kernel<<<NROWS, 256, 0, stream>>>(x, Wa, ba, Wb, bb, Alpha, Beta);
    // 3) K normalize
    knorm_kernel<<<(NROWS * NH) / 4, 256, 0, stream>>>(Kb);
    // 4) intra-chunk (parallel over 2048 chunks)
    chunk_intra<<<B_SZ * NH * NCH, 256, 0, stream>>>(Q, Kb, V, Alpha, Beta);
    // 5a) serial inter-chunk state recurrence (tiny); dS -> Sc in-place
    chunk_state<<<B_SZ * NH, 256, 0, stream>>>(Kb, Alpha, state, Sout);
    // 5b) parallel Y_inter + finalize to bf16
    y_finalize<<<B_SZ * NH * NCH, 256, 0, stream>>>(Q, Kb, V, Yb);
    // 6) output projection (bf16 MFMA)
    out_gemm_bf16<<<dim3(DM / 128, NROWS / 128), 256, 0, stream>>>(Yb, WoT, out);
}

// Round 5
// 418.728 us; speedup vs baseline: 6.7572x; 1.3084x over previous
//
#include <hip/hip_runtime.h>
#include <hip/hip_bf16.h>
#include <math.h>

// Problem constants
#define B_SZ   4
#define T_LEN  2048
#define DM     1024
#define NH     16
#define DH     64
#define INNER  1024          // NH*DH
#define NROWS  (B_SZ*T_LEN)  // 8192
#define NQ     (NROWS*INNER) // elements per Q/K/V/Y buffer
#define CH     64            // chunk length
#define NCH    (T_LEN/CH)    // 32 chunks

typedef __bf16 bf16x8 __attribute__((ext_vector_type(8)));
typedef __bf16 bf16x4 __attribute__((ext_vector_type(4)));
typedef float  f32x4  __attribute__((ext_vector_type(4)));
typedef __attribute__((address_space(3))) void*       lds_vp;
typedef const __attribute__((address_space(1))) void* gbl_vp;

// Swizzled index into a 64x64 bf16 LDS tile: 8-elem blocks rotated by row>>2.
// Row-major bf16x4 stores land conflict-free; transposed scalar stores and
// bf16x8 fragment reads are ~4-way (1.58x, m136) instead of 16-32-way.
__device__ __forceinline__ int swz(int row, int col) {
    return (row << 6) + ((((col >> 3) + (row >> 2)) & 7) << 3) + (col & 7);
}

// ---------------------------------------------------------------------------
// fp32 -> bf16 cast (x). One float4 per thread.
// ---------------------------------------------------------------------------
__global__ __launch_bounds__(256) void cast_bf16(const float* __restrict__ in,
                                                 __bf16* __restrict__ out) {
    const size_t i = (size_t)blockIdx.x * 256 + threadIdx.x;
    const float4 v = ((const float4*)in)[i];
    bf16x4 o;
    o[0] = (__bf16)v.x; o[1] = (__bf16)v.y; o[2] = (__bf16)v.z; o[3] = (__bf16)v.w;
    *(bf16x4*)(out + 4 * i) = o;
}

// ---------------------------------------------------------------------------
// Weight transpose + cast: W (K x N fp32, row-major) -> WT (N x K bf16).
// ---------------------------------------------------------------------------
__global__ __launch_bounds__(256) void wt_cast_transpose(const float* __restrict__ Wq,
                                                         const float* __restrict__ Wk,
                                                         const float* __restrict__ Wv,
                                                         const float* __restrict__ Wo,
                                                         __bf16* __restrict__ WqT,
                                                         __bf16* __restrict__ WkT,
                                                         __bf16* __restrict__ WvT,
                                                         __bf16* __restrict__ WoT) {
    __shared__ float tile[64][65];
    const float* W;
    __bf16* WT;
    if      (blockIdx.z == 0) { W = Wq; WT = WqT; }
    else if (blockIdx.z == 1) { W = Wk; WT = WkT; }
    else if (blockIdx.z == 2) { W = Wv; WT = WvT; }
    else                      { W = Wo; WT = WoT; }

    const int k0 = blockIdx.y * 64, n0 = blockIdx.x * 64;
    const int tr  = threadIdx.x >> 4;        // 0..15
    const int tc4 = (threadIdx.x & 15) * 4;  // 0..60

#pragma unroll
    for (int r = 0; r < 4; r++) {
        const int k = tr + 16 * r;
        const float4 v = *(const float4*)(W + (size_t)(k0 + k) * DM + n0 + tc4);
        tile[k][tc4 + 0] = v.x;
        tile[k][tc4 + 1] = v.y;
        tile[k][tc4 + 2] = v.z;
        tile[k][tc4 + 3] = v.w;
    }
    __syncthreads();
#pragma unroll
    for (int r = 0; r < 4; r++) {
        const int n = tr + 16 * r;
        bf16x4 o;
#pragma unroll
        for (int j = 0; j < 4; j++) o[j] = (__bf16)tile[tc4 + j][n];
        *(bf16x4*)(WT + (size_t)(n0 + n) * DM + k0 + tc4) = o;
    }
}

// ---------------------------------------------------------------------------
// bf16 MFMA GEMM (m97 structure): C[M x N] = A[M x K] * BT[N x K]^T.
// ---------------------------------------------------------------------------
__device__ __forceinline__ void gemm_bf16_body(const __bf16* __restrict__ A,
                                               const __bf16* __restrict__ BT,
                                               float* __restrict__ C,
                                               int Ndim, int Kdim) {
    __shared__ __align__(16) __bf16 lA[128 * 32];
    __shared__ __align__(16) __bf16 lB[128 * 32];

    const int tid  = threadIdx.x;
    const int wid  = tid >> 6;
    const int lane = tid & 63;
    const int m0 = blockIdx.y * 128, n0 = blockIdx.x * 128;
    const int wm = (wid >> 1) * 64, wn = (wid & 1) * 64;

    f32x4 acc[4][4];
#pragma unroll
    for (int i = 0; i < 4; i++)
#pragma unroll
        for (int j = 0; j < 4; j++) acc[i][j] = (f32x4)0.f;

    const int srow = wid * 32 + (lane >> 2);
    const int scol = (lane & 3) * 8;
    const __bf16* gA = A  + (size_t)(m0 + srow) * Kdim + scol;
    const __bf16* gB = BT + (size_t)(n0 + srow) * Kdim + scol;

    const int qoff = (lane >> 4) * 8;
    const int frow = lane & 15;

    for (int k0 = 0; k0 < Kdim; k0 += 32) {
        __syncthreads();
#pragma unroll
        for (int i = 0; i < 2; i++) {
            __builtin_amdgcn_global_load_lds((gbl_vp)(gA + k0 + (size_t)i * 16 * Kdim),
                                             (lds_vp)(&lA[(wid * 32 + i * 16) * 32]),
                                             16, 0, 0);
            __builtin_amdgcn_global_load_lds((gbl_vp)(gB + k0 + (size_t)i * 16 * Kdim),
                                             (lds_vp)(&lB[(wid * 32 + i * 16) * 32]),
                                             16, 0, 0);
        }
        __syncthreads();

        bf16x8 af[4], bfr[4];
#pragma unroll
        for (int t = 0; t < 4; t++) {
            af[t]  = *(const bf16x8*)&lA[(wm + t * 16 + frow) * 32 + qoff];
            bfr[t] = *(const bf16x8*)&lB[(wn + t * 16 + frow) * 32 + qoff];
        }
#pragma unroll
        for (int mi = 0; mi < 4; mi++)
#pragma unroll
            for (int nj = 0; nj < 4; nj++)
                acc[mi][nj] = __builtin_amdgcn_mfma_f32_16x16x32_bf16(
                    af[mi], bfr[nj], acc[mi][nj], 0, 0, 0);
    }

    const int cr = (lane >> 4) * 4, cc = lane & 15;
#pragma unroll
    for (int mi = 0; mi < 4; mi++) {
#pragma unroll
        for (int nj = 0; nj < 4; nj++) {
            float* Cp = C + (size_t)(m0 + wm + mi * 16 + cr) * Ndim + n0 + wn + nj * 16 + cc;
#pragma unroll
            for (int r = 0; r < 4; r++) Cp[(size_t)r * Ndim] = acc[mi][nj][r];
        }
    }
}

__global__ __launch_bounds__(256) void qkv_gemm_bf16(const __bf16* __restrict__ xb,
                                                     const __bf16* __restrict__ WqT,
                                                     const __bf16* __restrict__ WkT,
                                                     const __bf16* __restrict__ WvT,
                                                     float* __restrict__ Q,
                                                     float* __restrict__ K_,
                                                     float* __restrict__ V) {
    const __bf16* BT = (blockIdx.z == 0) ? WqT : ((blockIdx.z == 1) ? WkT : WvT);
    float*        Cm = (blockIdx.z == 0) ? Q   : ((blockIdx.z == 1) ? K_  : V);
    gemm_bf16_body(xb, BT, Cm, INNER, DM);
}

__global__ __launch_bounds__(256) void out_gemm_bf16(const __bf16* __restrict__ Yb,
                                                     const __bf16* __restrict__ WoT,
                                                     float* __restrict__ Cout) {
    gemm_bf16_body(Yb, WoT, Cout, DM, INNER);
}

// ---------------------------------------------------------------------------
// Gates: alpha = sigmoid(x@Wa + ba), beta = sigmoid(x@Wb + bb).
// ---------------------------------------------------------------------------
__global__ __launch_bounds__(256) void gates_kernel(const float* __restrict__ x,
                                                    const float* __restrict__ Wa,
                                                    const float* __restrict__ ba,
                                                    const float* __restrict__ Wb,
                                                    const float* __restrict__ bb,
                                                    float* __restrict__ Alpha,
                                                    float* __restrict__ Beta) {
    const int n = blockIdx.x;
    const int t = threadIdx.x;
    __shared__ float xs[DM];
    __shared__ float red[2][16][16];

    ((float4*)xs)[t] = ((const float4*)(x + n * DM))[t];
    __syncthreads();

    const int h = t & 15, seg = t >> 4;
    float pa = 0.f, pb = 0.f;
    const int k0 = seg * 64;
#pragma unroll 8
    for (int k = k0; k < k0 + 64; k++) {
        const float xv = xs[k];
        pa += xv * Wa[k * NH + h];
        pb += xv * Wb[k * NH + h];
    }
    red[0][seg][h] = pa;
    red[1][seg][h] = pb;
    __syncthreads();

    if (t < 32) {
        const int g = t >> 4, hh = t & 15;
        float s = 0.f;
#pragma unroll
        for (int sg = 0; sg < 16; sg++) s += red[g][sg][hh];
        s += (g == 0) ? ba[hh] : bb[hh];
        const float sig = 1.f / (1.f + __expf(-s));
        if (g == 0) Alpha[n * NH + hh] = sig;
        else        Beta[n * NH + hh]  = sig;
    }
}

// ---------------------------------------------------------------------------
// K row L2-normalize.
// ---------------------------------------------------------------------------
__global__ __launch_bounds__(256) void knorm_kernel(float* __restrict__ K) {
    const int row  = blockIdx.x * 4 + (threadIdx.x >> 6);
    const int lane = threadIdx.x & 63;
    float v = K[row * DH + lane];
    float ss = v * v;
#pragma unroll
    for (int m = 32; m >= 1; m >>= 1) ss += __shfl_xor(ss, m, 64);
    const float scale = 1.f / fmaxf(sqrtf(ss), 1e-12f);
    K[row * DH + lane] = v * scale;
}

// ---------------------------------------------------------------------------
// Pass A (MFMA): per (b,h,c), 256 threads = 4 waves.
//   gates prefix -> sla, sb, swd; chunk decay -> Dec (Alpha preserved!)
//   G = Q K^T                    (MFMA: A=Q rows t, BT=K rows s)
//   A[t][s] = mask * exp(la_t-la_s) * b_s * G   -> Ab (bf16, LDS)
//   Y_intra = A V   -> overwrites V   (MFMA: A=Ab, BT=VT rows i)
//   dS      = sum_s (swd_s k_s)(v_s)^T outer    -> overwrites K
//                                   (MFMA: A=VT rows i, BT=KTs rows j)
// Q is NOT modified (exp(la_t) scaling moved into chunk_y's epilogue).
// ---------------------------------------------------------------------------
__global__ __launch_bounds__(256) void chunk_ds(const float* __restrict__ Q,
                                                float* __restrict__ K,
                                                float* __restrict__ V,
                                                const float* __restrict__ Alpha,
                                                const float* __restrict__ Beta,
                                                float* __restrict__ Dec) {
    __shared__ __align__(16) __bf16 Qb[64 * 64];
    __shared__ __align__(16) __bf16 Kb[64 * 64];
    __shared__ __align__(16) __bf16 KTs[64 * 64];  // [j][s] = swd_s * K[s][j]
    __shared__ __align__(16) __bf16 VTb[64 * 64];  // [i][s] = V[s][i]
    __shared__ __align__(16) __bf16 Ab[64 * 64];   // [t][s]
    __shared__ float sla[64], sb[64], swd[64];

    const int blk = blockIdx.x;
    const int c = blk & 31, h = (blk >> 5) & 15, b = blk >> 9;
    const int t0 = c * CH;
    const int tid = threadIdx.x;
    const int wid = tid >> 6, lane = tid & 63;
    const int ty = tid >> 4, tx = tid & 15;
    const size_t rowbase = ((size_t)(b * T_LEN + t0) * NH + h) * DH;

    // prefetch staging rows into registers (coalesced float4 rows)
    float4 qv[4], kv[4], vv[4];
#pragma unroll
    for (int r = 0; r < 4; r++) {
        const size_t g = rowbase + (size_t)(ty + 16 * r) * INNER + tx * 4;
        qv[r] = *(const float4*)(Q + g);
        kv[r] = *(const float4*)(K + g);
        vv[r] = *(const float4*)(V + g);
    }

    // gates: prefix-sum of log(alpha) over the chunk (wave 0)
    if (tid < 64) {
        const int t = tid;
        const size_t ga = (size_t)(b * T_LEN + t0 + t) * NH + h;
        const float a  = Alpha[ga];
        const float bt = Beta[ga];
        float xx = logf(a);
#pragma unroll
        for (int off = 1; off < 64; off <<= 1) {
            const float y = __shfl_up(xx, off, 64);
            if (t >= off) xx += y;
        }
        const float la63 = __shfl(xx, 63, 64);
        sla[t] = xx;
        sb[t]  = bt;
        swd[t] = bt * __expf(la63 - xx);
        if (t == 63) Dec[(size_t)(b * NH + h) * NCH + c] = __expf(la63);
    }
    __syncthreads();

    // stage to LDS (swizzled); KTs needs swd -> after the barrier
#pragma unroll
    for (int r = 0; r < 4; r++) {
        const int row = ty + 16 * r;
        const int c0  = tx * 4;
        bf16x4 qb4, kb4;
        qb4[0] = (__bf16)qv[r].x; qb4[1] = (__bf16)qv[r].y;
        qb4[2] = (__bf16)qv[r].z; qb4[3] = (__bf16)qv[r].w;
        kb4[0] = (__bf16)kv[r].x; kb4[1] = (__bf16)kv[r].y;
        kb4[2] = (__bf16)kv[r].z; kb4[3] = (__bf16)kv[r].w;
        *(bf16x4*)&Qb[swz(row, c0)] = qb4;
        *(bf16x4*)&Kb[swz(row, c0)] = kb4;
        const float w = swd[row];
        const float kk[4]  = {kv[r].x, kv[r].y, kv[r].z, kv[r].w};
        const float vvv[4] = {vv[r].x, vv[r].y, vv[r].z, vv[r].w};
#pragma unroll
        for (int d = 0; d < 4; d++) {
            KTs[swz(c0 + d, row)] = (__bf16)(w * kk[d]);
            VTb[swz(c0 + d, row)] = (__bf16)vvv[d];
        }
    }
    __syncthreads();

    const int quad = lane >> 4;
    const int frow = lane & 15;
    const int tw = wid * 16;   // this wave's 16-row output stripe

    // ---- G = Q K^T ----
    f32x4 accG[4];
#pragma unroll
    for (int i = 0; i < 4; i++) accG[i] = (f32x4)0.f;
#pragma unroll
    for (int ks = 0; ks < 2; ks++) {
        const int ko = quad * 8 + 32 * ks;
        const bf16x8 aq = *(const bf16x8*)&Qb[swz(tw + frow, ko)];
#pragma unroll
        for (int st = 0; st < 4; st++) {
            const bf16x8 bk = *(const bf16x8*)&Kb[swz(st * 16 + frow, ko)];
            accG[st] = __builtin_amdgcn_mfma_f32_16x16x32_bf16(aq, bk, accG[st], 0, 0, 0);
        }
    }
    // ---- mask -> Ab (C layout: row=quad*4+r, col=frow) ----
#pragma unroll
    for (int st = 0; st < 4; st++) {
#pragma unroll
        for (int r = 0; r < 4; r++) {
            const int t = tw + quad * 4 + r;
            const int s = st * 16 + frow;
            const float av = (s <= t) ? __expf(sla[t] - sla[s]) * sb[s] * accG[st][r] : 0.f;
            Ab[swz(t, s)] = (__bf16)av;
        }
    }
    __syncthreads();

    // ---- Y_intra = A V  and  dS = VT * KTs^T ----
    f32x4 accY[4], accD[4];
#pragma unroll
    for (int i = 0; i < 4; i++) { accY[i] = (f32x4)0.f; accD[i] = (f32x4)0.f; }
#pragma unroll
    for (int ks = 0; ks < 2; ks++) {
        const int ko = quad * 8 + 32 * ks;
        const bf16x8 aA = *(const bf16x8*)&Ab[swz(tw + frow, ko)];
        const bf16x8 aV = *(const bf16x8*)&VTb[swz(tw + frow, ko)];
#pragma unroll
        for (int jt = 0; jt < 4; jt++) {
            const bf16x8 bv = *(const bf16x8*)&VTb[swz(jt * 16 + frow, ko)];
            const bf16x8 bk = *(const bf16x8*)&KTs[swz(jt * 16 + frow, ko)];
            accY[jt] = __builtin_amdgcn_mfma_f32_16x16x32_bf16(aA, bv, accY[jt], 0, 0, 0);
            accD[jt] = __builtin_amdgcn_mfma_f32_16x16x32_bf16(aV, bk, accD[jt], 0, 0, 0);
        }
    }
    // write Yin over V, dS over K (this block's exclusive region)
#pragma unroll
    for (int jt = 0; jt < 4; jt++) {
#pragma unroll
        for (int r = 0; r < 4; r++) {
            const int row = tw + quad * 4 + r;
            const size_t g = rowbase + (size_t)row * INNER + jt * 16 + frow;
            V[g] = accY[jt][r];
            K[g] = accD[jt][r];
        }
    }
}

// ---------------------------------------------------------------------------
// Pass B1 (serial, tiny): S_{c+1} = Dec_c * S_c + dS_c over 32 chunks per
// (b,h).  Writes each PRE-update state S_c over the dS slot it consumed.
// ---------------------------------------------------------------------------
__global__ __launch_bounds__(256) void chunk_state(float* __restrict__ DS,
                                                   const float* __restrict__ Dec,
                                                   const float* __restrict__ state_in,
                                                   float* __restrict__ state_out) {
    const int blk = blockIdx.x;          // (b,h)
    const int b = blk >> 4, h = blk & 15;
    const int tid = threadIdx.x;
    const int w = tid >> 6;
    const int l = tid & 63;

    float S[16];
    {
        const float* st = state_in + ((size_t)(b * NH + h) * DH + l) * DH + 16 * w;
#pragma unroll
        for (int j4 = 0; j4 < 4; j4++)
            *(float4*)&S[4 * j4] = *(const float4*)(st + 4 * j4);
    }

    for (int c = 0; c < NCH; c++) {
        const int t0 = c * CH;
        const float decay = Dec[(size_t)(b * NH + h) * NCH + c];
        float* ds = DS + ((size_t)(b * T_LEN + t0 + l) * NH + h) * DH + 16 * w;
        float4 dv[4];
#pragma unroll
        for (int j4 = 0; j4 < 4; j4++) dv[j4] = *(const float4*)(ds + 4 * j4);
#pragma unroll
        for (int j4 = 0; j4 < 4; j4++) *(float4*)(ds + 4 * j4) = *(const float4*)&S[4 * j4];
#pragma unroll
        for (int j4 = 0; j4 < 4; j4++) {
            S[4 * j4 + 0] = decay * S[4 * j4 + 0] + dv[j4].x;
            S[4 * j4 + 1] = decay * S[4 * j4 + 1] + dv[j4].y;
            S[4 * j4 + 2] = decay * S[4 * j4 + 2] + dv[j4].z;
            S[4 * j4 + 3] = decay * S[4 * j4 + 3] + dv[j4].w;
        }
    }

    float* so = state_out + ((size_t)(b * NH + h) * DH + l) * DH + 16 * w;
#pragma unroll
    for (int j4 = 0; j4 < 4; j4++)
        *(float4*)(so + 4 * j4) = *(const float4*)&S[4 * j4];
}

// ---------------------------------------------------------------------------
// Pass B2 (MFMA): Y[t][i] = Yin[t][i] + exp(la_t) * sum_j Q[t][j] Sc[i][j],
// cast to bf16.  Per (b,h,c), 256 threads = 4 waves.
// ---------------------------------------------------------------------------
__global__ __launch_bounds__(256) void chunk_y(const float* __restrict__ Q,
                                               const float* __restrict__ Sc,
                                               const float* __restrict__ Yin,
                                               __bf16* __restrict__ Yb,
                                               const float* __restrict__ Alpha) {
    __shared__ __align__(16) __bf16 Qb[64 * 64];
    __shared__ __align__(16) __bf16 Scb[64 * 64];
    __shared__ float sexp[64];

    const int blk = blockIdx.x;
    const int c = blk & 31, h = (blk >> 5) & 15, b = blk >> 9;
    const int t0 = c * CH;
    const int tid = threadIdx.x;
    const int wid = tid >> 6, lane = tid & 63;
    const int ty = tid >> 4, tx = tid & 15;
    const size_t rowbase = ((size_t)(b * T_LEN + t0) * NH + h) * DH;

    float4 qv[4], sv[4];
#pragma unroll
    for (int r = 0; r < 4; r++) {
        const size_t g = rowbase + (size_t)(ty + 16 * r) * INNER + tx * 4;
        qv[r] = *(const float4*)(Q + g);
        sv[r] = *(const float4*)(Sc + g);
    }

    if (tid < 64) {
        const int t = tid;
        const size_t ga = (size_t)(b * T_LEN + t0 + t) * NH + h;
        float xx = logf(Alpha[ga]);
#pragma unroll
        for (int off = 1; off < 64; off <<= 1) {
            const float y = __shfl_up(xx, off, 64);
            if (t >= off) xx += y;
        }
        sexp[t] = __expf(xx);
    }
    __syncthreads();

#pragma unroll
    for (int r = 0; r < 4; r++) {
        const int row = ty + 16 * r;
        const int c0  = tx * 4;
        bf16x4 qb4, sb4;
        qb4[0] = (__bf16)qv[r].x; qb4[1] = (__bf16)qv[r].y;
        qb4[2] = (__bf16)qv[r].z; qb4[3] = (__bf16)qv[r].w;
        sb4[0] = (__bf16)sv[r].x; sb4[1] = (__bf16)sv[r].y;
        sb4[2] = (__bf16)sv[r].z; sb4[3] = (__bf16)sv[r].w;
        *(bf16x4*)&Qb[swz(row, c0)]  = qb4;
        *(bf16x4*)&Scb[swz(row, c0)] = sb4;
    }
    __syncthreads();

    const int quad = lane >> 4;
    const int frow = lane & 15;
    const int tw = wid * 16;

    f32x4 accU[4];
#pragma unroll
    for (int i = 0; i < 4; i++) accU[i] = (f32x4)0.f;
#pragma unroll
    for (int ks = 0; ks < 2; ks++) {
        const int ko = quad * 8 + 32 * ks;
        const bf16x8 aq = *(const bf16x8*)&Qb[swz(tw + frow, ko)];
#pragma unroll
        for (int it = 0; it < 4; it++) {
            const bf16x8 bs = *(const bf16x8*)&Scb[swz(it * 16 + frow, ko)];
            accU[it] = __builtin_amdgcn_mfma_f32_16x16x32_bf16(aq, bs, accU[it], 0, 0, 0);
        }
    }

#pragma unroll
    for (int it = 0; it < 4; it++) {
#pragma unroll
        for (int r = 0; r < 4; r++) {
            const int t = tw + quad * 4 + r;
            const size_t g = rowbase + (size_t)t * INNER + it * 16 + frow;
            Yb[g] = (__bf16)(sexp[t] * accU[it][r] + Yin[g]);
        }
    }
}

// ---------------------------------------------------------------------------
extern "C" void kernel_launch(void* const* d_in, const int* in_sizes, int n_in,
                              void* d_out, int out_size, void* d_ws, size_t ws_size,
                              hipStream_t stream) {
    const float* x     = (const float*)d_in[0];
    const float* state = (const float*)d_in[1];
    const float* Wq    = (const float*)d_in[2];
    const float* Wk    = (const float*)d_in[3];
    const float* Wv    = (const float*)d_in[4];
    const float* Wa    = (const float*)d_in[5];
    const float* ba    = (const float*)d_in[6];
    const float* Wb    = (const float*)d_in[7];
    const float* bb    = (const float*)d_in[8];
    const float* Wo    = (const float*)d_in[9];

    float* ws    = (float*)d_ws;
    float* Q     = ws;                          // q (preserved raw)
    float* Kb    = ws + (size_t)NQ;             // k -> dS (A) -> Sc (B1)
    float* V     = ws + 2 * (size_t)NQ;         // v -> Y_intra (A)
    float* Alpha = ws + 3 * (size_t)NQ;         // raw alpha (preserved)
    float* Beta  = Alpha + (size_t)NROWS * NH;
    float* Dec   = Beta + (size_t)NROWS * NH;   // per-chunk decay (B*NH*NCH)
    __bf16* xb   = (__bf16*)(Dec + (size_t)B_SZ * NH * NCH);
    __bf16* Yb   = xb;                          // reuse: xb dead after qkv gemm
    __bf16* WqT  = xb + (size_t)NQ;
    __bf16* WkT  = WqT + (size_t)DM * INNER;
    __bf16* WvT  = WkT + (size_t)DM * INNER;
    __bf16* WoT  = WvT + (size_t)DM * INNER;

    float* out  = (float*)d_out;                // (B,T,DM)
    float* Sout = out + (size_t)NQ;             // (B,H,D,D)

    // 0) casts
    cast_bf16<<<NQ / 1024, 256, 0, stream>>>(x, xb);
    wt_cast_transpose<<<dim3(16, 16, 4), 256, 0, stream>>>(Wq, Wk, Wv, Wo,
                                                           WqT, WkT, WvT, WoT);
    // 1) Q/K/V projections (bf16 MFMA)
    qkv_gemm_bf16<<<dim3(INNER / 128, NROWS / 128, 3), 256, 0, stream>>>(
        xb, WqT, WkT, WvT, Q, Kb, V);
    // 2) gates
    gates_kernel<<<NROWS, 256, 0, stream>>>(x, Wa, ba, Wb, bb, Alpha, Beta);
    // 3) K normalize
    knorm_kernel<<<(NROWS * NH) / 4, 256, 0, stream>>>(Kb);
    // 4) intra-chunk MFMA: Y_intra -> V, dS -> Kb, decay -> Dec
    chunk_ds<<<B_SZ * NH * NCH, 256, 0, stream>>>(Q, Kb, V, Alpha, Beta, Dec);
    // 5a) serial inter-chunk state recurrence; dS -> Sc in-place
    chunk_state<<<B_SZ * NH, 256, 0, stream>>>(Kb, Dec, state, Sout);
    // 5b) parallel Y_inter MFMA + finalize to bf16
    chunk_y<<<B_SZ * NH * NCH, 256, 0, stream>>>(Q, Kb, V, Yb, Alpha);
    // 6) output projection (bf16 MFMA)
    out_gemm_bf16<<<dim3(DM / 128, NROWS / 128), 256, 0, stream>>>(Yb, WoT, out);
}

// Round 6
// 345.456 us; speedup vs baseline: 8.1904x; 1.2121x over previous
//
#include <hip/hip_runtime.h>
#include <hip/hip_bf16.h>
#include <math.h>

// Problem constants
#define B_SZ   4
#define T_LEN  2048
#define DM     1024
#define NH     16
#define DH     64
#define INNER  1024          // NH*DH
#define NROWS  (B_SZ*T_LEN)  // 8192
#define NQ     (NROWS*INNER) // elements per Q/K/V/Y buffer
#define CH     64            // chunk length
#define NCH    (T_LEN/CH)    // 32 chunks

typedef __bf16 bf16x8 __attribute__((ext_vector_type(8)));
typedef __bf16 bf16x4 __attribute__((ext_vector_type(4)));
typedef float  f32x4  __attribute__((ext_vector_type(4)));
typedef __attribute__((address_space(3))) void*       lds_vp;
typedef const __attribute__((address_space(1))) void* gbl_vp;

// Swizzled index into a 64x64 bf16 LDS tile: 8-elem blocks rotated by row>>2.
__device__ __forceinline__ int swz(int row, int col) {
    return (row << 6) + ((((col >> 3) + (row >> 2)) & 7) << 3) + (col & 7);
}

// ---------------------------------------------------------------------------
// Weight transpose + cast: W (K x N fp32, row-major) -> WT (N x K bf16).
// ---------------------------------------------------------------------------
__global__ __launch_bounds__(256) void wt_cast_transpose(const float* __restrict__ Wq,
                                                         const float* __restrict__ Wk,
                                                         const float* __restrict__ Wv,
                                                         const float* __restrict__ Wo,
                                                         __bf16* __restrict__ WqT,
                                                         __bf16* __restrict__ WkT,
                                                         __bf16* __restrict__ WvT,
                                                         __bf16* __restrict__ WoT) {
    __shared__ float tile[64][65];
    const float* W;
    __bf16* WT;
    if      (blockIdx.z == 0) { W = Wq; WT = WqT; }
    else if (blockIdx.z == 1) { W = Wk; WT = WkT; }
    else if (blockIdx.z == 2) { W = Wv; WT = WvT; }
    else                      { W = Wo; WT = WoT; }

    const int k0 = blockIdx.y * 64, n0 = blockIdx.x * 64;
    const int tr  = threadIdx.x >> 4;        // 0..15
    const int tc4 = (threadIdx.x & 15) * 4;  // 0..60

#pragma unroll
    for (int r = 0; r < 4; r++) {
        const int k = tr + 16 * r;
        const float4 v = *(const float4*)(W + (size_t)(k0 + k) * DM + n0 + tc4);
        tile[k][tc4 + 0] = v.x;
        tile[k][tc4 + 1] = v.y;
        tile[k][tc4 + 2] = v.z;
        tile[k][tc4 + 3] = v.w;
    }
    __syncthreads();
#pragma unroll
    for (int r = 0; r < 4; r++) {
        const int n = tr + 16 * r;
        bf16x4 o;
#pragma unroll
        for (int j = 0; j < 4; j++) o[j] = (__bf16)tile[tc4 + j][n];
        *(bf16x4*)(WT + (size_t)(n0 + n) * DM + k0 + tc4) = o;
    }
}

// ---------------------------------------------------------------------------
// bf16 MFMA GEMM (m97 structure): C[M x N] = A[M x K] * BT[N x K]^T.
// CT = float or __bf16 (output dtype).
// ---------------------------------------------------------------------------
template <typename CT>
__device__ __forceinline__ void gemm_bf16_body(const __bf16* __restrict__ A,
                                               const __bf16* __restrict__ BT,
                                               CT* __restrict__ C,
                                               int Ndim, int Kdim) {
    __shared__ __align__(16) __bf16 lA[128 * 32];
    __shared__ __align__(16) __bf16 lB[128 * 32];

    const int tid  = threadIdx.x;
    const int wid  = tid >> 6;
    const int lane = tid & 63;
    const int m0 = blockIdx.y * 128, n0 = blockIdx.x * 128;
    const int wm = (wid >> 1) * 64, wn = (wid & 1) * 64;

    f32x4 acc[4][4];
#pragma unroll
    for (int i = 0; i < 4; i++)
#pragma unroll
        for (int j = 0; j < 4; j++) acc[i][j] = (f32x4)0.f;

    const int srow = wid * 32 + (lane >> 2);
    const int scol = (lane & 3) * 8;
    const __bf16* gA = A  + (size_t)(m0 + srow) * Kdim + scol;
    const __bf16* gB = BT + (size_t)(n0 + srow) * Kdim + scol;

    const int qoff = (lane >> 4) * 8;
    const int frow = lane & 15;

    for (int k0 = 0; k0 < Kdim; k0 += 32) {
        __syncthreads();
#pragma unroll
        for (int i = 0; i < 2; i++) {
            __builtin_amdgcn_global_load_lds((gbl_vp)(gA + k0 + (size_t)i * 16 * Kdim),
                                             (lds_vp)(&lA[(wid * 32 + i * 16) * 32]),
                                             16, 0, 0);
            __builtin_amdgcn_global_load_lds((gbl_vp)(gB + k0 + (size_t)i * 16 * Kdim),
                                             (lds_vp)(&lB[(wid * 32 + i * 16) * 32]),
                                             16, 0, 0);
        }
        __syncthreads();

        bf16x8 af[4], bfr[4];
#pragma unroll
        for (int t = 0; t < 4; t++) {
            af[t]  = *(const bf16x8*)&lA[(wm + t * 16 + frow) * 32 + qoff];
            bfr[t] = *(const bf16x8*)&lB[(wn + t * 16 + frow) * 32 + qoff];
        }
#pragma unroll
        for (int mi = 0; mi < 4; mi++)
#pragma unroll
            for (int nj = 0; nj < 4; nj++)
                acc[mi][nj] = __builtin_amdgcn_mfma_f32_16x16x32_bf16(
                    af[mi], bfr[nj], acc[mi][nj], 0, 0, 0);
    }

    const int cr = (lane >> 4) * 4, cc = lane & 15;
#pragma unroll
    for (int mi = 0; mi < 4; mi++) {
#pragma unroll
        for (int nj = 0; nj < 4; nj++) {
            CT* Cp = C + (size_t)(m0 + wm + mi * 16 + cr) * Ndim + n0 + wn + nj * 16 + cc;
#pragma unroll
            for (int r = 0; r < 4; r++) Cp[(size_t)r * Ndim] = (CT)acc[mi][nj][r];
        }
    }
}

__global__ __launch_bounds__(256) void qkv_gemm_bf16(const __bf16* __restrict__ xb,
                                                     const __bf16* __restrict__ WqT,
                                                     const __bf16* __restrict__ WkT,
                                                     const __bf16* __restrict__ WvT,
                                                     __bf16* __restrict__ Q,
                                                     __bf16* __restrict__ K_,
                                                     __bf16* __restrict__ V) {
    const __bf16* BT = (blockIdx.z == 0) ? WqT : ((blockIdx.z == 1) ? WkT : WvT);
    __bf16*       Cm = (blockIdx.z == 0) ? Q   : ((blockIdx.z == 1) ? K_  : V);
    gemm_bf16_body<__bf16>(xb, BT, Cm, INNER, DM);
}

__global__ __launch_bounds__(256) void out_gemm_bf16(const __bf16* __restrict__ Yb,
                                                     const __bf16* __restrict__ WoT,
                                                     float* __restrict__ Cout) {
    gemm_bf16_body<float>(Yb, WoT, Cout, DM, INNER);
}

// ---------------------------------------------------------------------------
// Gates + x cast: alpha/beta = sigmoid(x@W + b); also writes xb = bf16(x).
// ---------------------------------------------------------------------------
__global__ __launch_bounds__(256) void gates_kernel(const float* __restrict__ x,
                                                    const float* __restrict__ Wa,
                                                    const float* __restrict__ ba,
                                                    const float* __restrict__ Wb,
                                                    const float* __restrict__ bb,
                                                    float* __restrict__ Alpha,
                                                    float* __restrict__ Beta,
                                                    __bf16* __restrict__ xb) {
    const int n = blockIdx.x;
    const int t = threadIdx.x;
    __shared__ float xs[DM];
    __shared__ float red[2][16][16];

    const float4 v = ((const float4*)(x + n * DM))[t];
    ((float4*)xs)[t] = v;
    {
        bf16x4 o;
        o[0] = (__bf16)v.x; o[1] = (__bf16)v.y; o[2] = (__bf16)v.z; o[3] = (__bf16)v.w;
        *(bf16x4*)(xb + (size_t)n * DM + t * 4) = o;
    }
    __syncthreads();

    const int h = t & 15, seg = t >> 4;
    float pa = 0.f, pb = 0.f;
    const int k0 = seg * 64;
#pragma unroll 8
    for (int k = k0; k < k0 + 64; k++) {
        const float xv = xs[k];
        pa += xv * Wa[k * NH + h];
        pb += xv * Wb[k * NH + h];
    }
    red[0][seg][h] = pa;
    red[1][seg][h] = pb;
    __syncthreads();

    if (t < 32) {
        const int g = t >> 4, hh = t & 15;
        float s = 0.f;
#pragma unroll
        for (int sg = 0; sg < 16; sg++) s += red[g][sg][hh];
        s += (g == 0) ? ba[hh] : bb[hh];
        const float sig = 1.f / (1.f + __expf(-s));
        if (g == 0) Alpha[n * NH + hh] = sig;
        else        Beta[n * NH + hh]  = sig;
    }
}

// ---------------------------------------------------------------------------
// Pass A (MFMA, bf16 I/O): per (b,h,c), 256 threads = 4 waves.
//   K rows L2-normalized in-register (knorm fused).
//   G = Q K^T ; A = mask*exp(la_t-la_s)*b_s*G ; Y_intra = A V -> V (bf16)
//   dS = sum_s swd_s v_s k_s^T -> DS (fp32)
// ---------------------------------------------------------------------------
__global__ __launch_bounds__(256) void chunk_ds(const __bf16* __restrict__ Q,
                                                const __bf16* __restrict__ K,
                                                __bf16* __restrict__ V,
                                                const float* __restrict__ Alpha,
                                                const float* __restrict__ Beta,
                                                float* __restrict__ Dec,
                                                float* __restrict__ DS) {
    __shared__ __align__(16) __bf16 Qb[64 * 64];
    __shared__ __align__(16) __bf16 Kb[64 * 64];
    __shared__ __align__(16) __bf16 KTs[64 * 64];  // [j][s] = swd_s * kn[s][j]
    __shared__ __align__(16) __bf16 VTb[64 * 64];  // [i][s] = V[s][i]
    __shared__ __align__(16) __bf16 Ab[64 * 64];   // [t][s]
    __shared__ float sla[64], sb[64], swd[64];

    const int blk = blockIdx.x;
    const int c = blk & 31, h = (blk >> 5) & 15, b = blk >> 9;
    const int t0 = c * CH;
    const int tid = threadIdx.x;
    const int wid = tid >> 6, lane = tid & 63;
    const size_t rowbase = ((size_t)(b * T_LEN + t0) * NH + h) * DH;

    // prefetch (16B bf16x8 per matrix per round)
    const int srow = tid >> 3;          // 0..31
    const int scol = (tid & 7) * 8;     // 0..56
    bf16x8 q8[2], k8[2], v8[2];
#pragma unroll
    for (int r = 0; r < 2; r++) {
        const size_t g = rowbase + (size_t)(srow + 32 * r) * INNER + scol;
        q8[r] = *(const bf16x8*)(Q + g);
        k8[r] = *(const bf16x8*)(K + g);
        v8[r] = *(const bf16x8*)(V + g);
    }

    // gates: prefix-sum of log(alpha) over the chunk (wave 0)
    if (tid < 64) {
        const int t = tid;
        const size_t ga = (size_t)(b * T_LEN + t0 + t) * NH + h;
        const float a  = Alpha[ga];
        const float bt = Beta[ga];
        float xx = logf(a);
#pragma unroll
        for (int off = 1; off < 64; off <<= 1) {
            const float y = __shfl_up(xx, off, 64);
            if (t >= off) xx += y;
        }
        const float la63 = __shfl(xx, 63, 64);
        sla[t] = xx;
        sb[t]  = bt;
        swd[t] = bt * __expf(la63 - xx);
        if (t == 63) Dec[(size_t)(b * NH + h) * NCH + c] = __expf(la63);
    }
    __syncthreads();

    // stage to LDS: normalize k rows (8 lanes per row -> 3 shfl_xor)
#pragma unroll
    for (int r = 0; r < 2; r++) {
        const int row = srow + 32 * r;
        float kf[8];
        float ss = 0.f;
#pragma unroll
        for (int j = 0; j < 8; j++) { kf[j] = (float)k8[r][j]; ss += kf[j] * kf[j]; }
        ss += __shfl_xor(ss, 1, 64);
        ss += __shfl_xor(ss, 2, 64);
        ss += __shfl_xor(ss, 4, 64);
        const float scale = 1.f / fmaxf(sqrtf(ss), 1e-12f);
        const float w = swd[row];
        bf16x8 kn8;
#pragma unroll
        for (int j = 0; j < 8; j++) {
            const float kn = kf[j] * scale;
            kn8[j] = (__bf16)kn;
            KTs[swz(scol + j, row)] = (__bf16)(w * kn);
            VTb[swz(scol + j, row)] = v8[r][j];
        }
        *(bf16x8*)&Qb[swz(row, scol)] = q8[r];
        *(bf16x8*)&Kb[swz(row, scol)] = kn8;
    }
    __syncthreads();

    const int quad = lane >> 4;
    const int frow = lane & 15;
    const int tw = wid * 16;   // this wave's 16-row output stripe

    // ---- G = Q K^T ----
    f32x4 accG[4];
#pragma unroll
    for (int i = 0; i < 4; i++) accG[i] = (f32x4)0.f;
#pragma unroll
    for (int ks = 0; ks < 2; ks++) {
        const int ko = quad * 8 + 32 * ks;
        const bf16x8 aq = *(const bf16x8*)&Qb[swz(tw + frow, ko)];
#pragma unroll
        for (int st = 0; st < 4; st++) {
            const bf16x8 bk = *(const bf16x8*)&Kb[swz(st * 16 + frow, ko)];
            accG[st] = __builtin_amdgcn_mfma_f32_16x16x32_bf16(aq, bk, accG[st], 0, 0, 0);
        }
    }
    // ---- mask -> Ab (C layout: row=quad*4+r, col=frow) ----
#pragma unroll
    for (int st = 0; st < 4; st++) {
#pragma unroll
        for (int r = 0; r < 4; r++) {
            const int t = tw + quad * 4 + r;
            const int s = st * 16 + frow;
            const float av = (s <= t) ? __expf(sla[t] - sla[s]) * sb[s] * accG[st][r] : 0.f;
            Ab[swz(t, s)] = (__bf16)av;
        }
    }
    __syncthreads();

    // ---- Y_intra = A V  and  dS = VT * KTs^T ----
    f32x4 accY[4], accD[4];
#pragma unroll
    for (int i = 0; i < 4; i++) { accY[i] = (f32x4)0.f; accD[i] = (f32x4)0.f; }
#pragma unroll
    for (int ks = 0; ks < 2; ks++) {
        const int ko = quad * 8 + 32 * ks;
        const bf16x8 aA = *(const bf16x8*)&Ab[swz(tw + frow, ko)];
        const bf16x8 aV = *(const bf16x8*)&VTb[swz(tw + frow, ko)];
#pragma unroll
        for (int jt = 0; jt < 4; jt++) {
            const bf16x8 bv = *(const bf16x8*)&VTb[swz(jt * 16 + frow, ko)];
            const bf16x8 bk = *(const bf16x8*)&KTs[swz(jt * 16 + frow, ko)];
            accY[jt] = __builtin_amdgcn_mfma_f32_16x16x32_bf16(aA, bv, accY[jt], 0, 0, 0);
            accD[jt] = __builtin_amdgcn_mfma_f32_16x16x32_bf16(aV, bk, accD[jt], 0, 0, 0);
        }
    }
    // write Y_intra (bf16) over V, dS (fp32) to DS
#pragma unroll
    for (int jt = 0; jt < 4; jt++) {
#pragma unroll
        for (int r = 0; r < 4; r++) {
            const int row = tw + quad * 4 + r;
            const size_t g = rowbase + (size_t)row * INNER + jt * 16 + frow;
            V[g]  = (__bf16)accY[jt][r];
            DS[g] = accD[jt][r];
        }
    }
}

// ---------------------------------------------------------------------------
// Pass B1 (serial, tiny): S_{c+1} = Dec_c * S_c + dS_c over 32 chunks per
// (b,h).  Writes each PRE-update state S_c over the dS slot it consumed.
// ---------------------------------------------------------------------------
__global__ __launch_bounds__(256) void chunk_state(float* __restrict__ DS,
                                                   const float* __restrict__ Dec,
                                                   const float* __restrict__ state_in,
                                                   float* __restrict__ state_out) {
    const int blk = blockIdx.x;          // (b,h)
    const int b = blk >> 4, h = blk & 15;
    const int tid = threadIdx.x;
    const int w = tid >> 6;
    const int l = tid & 63;

    float S[16];
    {
        const float* st = state_in + ((size_t)(b * NH + h) * DH + l) * DH + 16 * w;
#pragma unroll
        for (int j4 = 0; j4 < 4; j4++)
            *(float4*)&S[4 * j4] = *(const float4*)(st + 4 * j4);
    }

    for (int c = 0; c < NCH; c++) {
        const int t0 = c * CH;
        const float decay = Dec[(size_t)(b * NH + h) * NCH + c];
        float* ds = DS + ((size_t)(b * T_LEN + t0 + l) * NH + h) * DH + 16 * w;
        float4 dv[4];
#pragma unroll
        for (int j4 = 0; j4 < 4; j4++) dv[j4] = *(const float4*)(ds + 4 * j4);
#pragma unroll
        for (int j4 = 0; j4 < 4; j4++) *(float4*)(ds + 4 * j4) = *(const float4*)&S[4 * j4];
#pragma unroll
        for (int j4 = 0; j4 < 4; j4++) {
            S[4 * j4 + 0] = decay * S[4 * j4 + 0] + dv[j4].x;
            S[4 * j4 + 1] = decay * S[4 * j4 + 1] + dv[j4].y;
            S[4 * j4 + 2] = decay * S[4 * j4 + 2] + dv[j4].z;
            S[4 * j4 + 3] = decay * S[4 * j4 + 3] + dv[j4].w;
        }
    }

    float* so = state_out + ((size_t)(b * NH + h) * DH + l) * DH + 16 * w;
#pragma unroll
    for (int j4 = 0; j4 < 4; j4++)
        *(float4*)(so + 4 * j4) = *(const float4*)&S[4 * j4];
}

// ---------------------------------------------------------------------------
// Pass B2 (MFMA): Yb[t][i] = bf16( Yb[t][i] + exp(la_t)*sum_j Q[t][j]Sc[i][j] )
// in-place over the Y_intra buffer.  Per (b,h,c), 256 threads = 4 waves.
// ---------------------------------------------------------------------------
__global__ __launch_bounds__(256) void chunk_y(const __bf16* __restrict__ Q,
                                               const float* __restrict__ Sc,
                                               __bf16* __restrict__ Yb,
                                               const float* __restrict__ Alpha) {
    __shared__ __align__(16) __bf16 Qb[64 * 64];
    __shared__ __align__(16) __bf16 Scb[64 * 64];
    __shared__ float sexp[64];

    const int blk = blockIdx.x;
    const int c = blk & 31, h = (blk >> 5) & 15, b = blk >> 9;
    const int t0 = c * CH;
    const int tid = threadIdx.x;
    const int wid = tid >> 6, lane = tid & 63;
    const int ty = tid >> 4, tx = tid & 15;
    const size_t rowbase = ((size_t)(b * T_LEN + t0) * NH + h) * DH;

    // prefetch Q (bf16x8) and Sc (float4)
    const int srow = tid >> 3;
    const int scol = (tid & 7) * 8;
    bf16x8 q8[2];
#pragma unroll
    for (int r = 0; r < 2; r++)
        q8[r] = *(const bf16x8*)(Q + rowbase + (size_t)(srow + 32 * r) * INNER + scol);
    float4 sv[4];
#pragma unroll
    for (int r = 0; r < 4; r++)
        sv[r] = *(const float4*)(Sc + rowbase + (size_t)(ty + 16 * r) * INNER + tx * 4);

    if (tid < 64) {
        const int t = tid;
        const size_t ga = (size_t)(b * T_LEN + t0 + t) * NH + h;
        float xx = logf(Alpha[ga]);
#pragma unroll
        for (int off = 1; off < 64; off <<= 1) {
            const float y = __shfl_up(xx, off, 64);
            if (t >= off) xx += y;
        }
        sexp[t] = __expf(xx);
    }

#pragma unroll
    for (int r = 0; r < 2; r++)
        *(bf16x8*)&Qb[swz(srow + 32 * r, scol)] = q8[r];
#pragma unroll
    for (int r = 0; r < 4; r++) {
        bf16x4 o;
        o[0] = (__bf16)sv[r].x; o[1] = (__bf16)sv[r].y;
        o[2] = (__bf16)sv[r].z; o[3] = (__bf16)sv[r].w;
        *(bf16x4*)&Scb[swz(ty + 16 * r, tx * 4)] = o;
    }
    __syncthreads();

    const int quad = lane >> 4;
    const int frow = lane & 15;
    const int tw = wid * 16;

    f32x4 accU[4];
#pragma unroll
    for (int i = 0; i < 4; i++) accU[i] = (f32x4)0.f;
#pragma unroll
    for (int ks = 0; ks < 2; ks++) {
        const int ko = quad * 8 + 32 * ks;
        const bf16x8 aq = *(const bf16x8*)&Qb[swz(tw + frow, ko)];
#pragma unroll
        for (int it = 0; it < 4; it++) {
            const bf16x8 bs = *(const bf16x8*)&Scb[swz(it * 16 + frow, ko)];
            accU[it] = __builtin_amdgcn_mfma_f32_16x16x32_bf16(aq, bs, accU[it], 0, 0, 0);
        }
    }

#pragma unroll
    for (int it = 0; it < 4; it++) {
#pragma unroll
        for (int r = 0; r < 4; r++) {
            const int t = tw + quad * 4 + r;
            const size_t g = rowbase + (size_t)t * INNER + it * 16 + frow;
            Yb[g] = (__bf16)(sexp[t] * accU[it][r] + (float)Yb[g]);
        }
    }
}

// ---------------------------------------------------------------------------
extern "C" void kernel_launch(void* const* d_in, const int* in_sizes, int n_in,
                              void* d_out, int out_size, void* d_ws, size_t ws_size,
                              hipStream_t stream) {
    const float* x     = (const float*)d_in[0];
    const float* state = (const float*)d_in[1];
    const float* Wq    = (const float*)d_in[2];
    const float* Wk    = (const float*)d_in[3];
    const float* Wv    = (const float*)d_in[4];
    const float* Wa    = (const float*)d_in[5];
    const float* ba    = (const float*)d_in[6];
    const float* Wb    = (const float*)d_in[7];
    const float* bb    = (const float*)d_in[8];
    const float* Wo    = (const float*)d_in[9];

    __bf16* Qb   = (__bf16*)d_ws;               // NQ bf16 (raw q, preserved)
    __bf16* Kbf  = Qb + (size_t)NQ;             // NQ bf16 (raw k; normalized in chunk_ds)
    __bf16* Vbf  = Kbf + (size_t)NQ;            // NQ bf16 (v -> Y_intra -> Y final)
    float*  DS   = (float*)(Vbf + (size_t)NQ);  // NQ fp32 (dS -> Sc in-place)
    float*  Alpha= DS + (size_t)NQ;
    float*  Beta = Alpha + (size_t)NROWS * NH;
    float*  Dec  = Beta + (size_t)NROWS * NH;   // per-chunk decay
    __bf16* xb   = (__bf16*)(Dec + (size_t)B_SZ * NH * NCH);
    __bf16* WqT  = xb + (size_t)NQ;
    __bf16* WkT  = WqT + (size_t)DM * INNER;
    __bf16* WvT  = WkT + (size_t)DM * INNER;
    __bf16* WoT  = WvT + (size_t)DM * INNER;

    float* out  = (float*)d_out;                // (B,T,DM)
    float* Sout = out + (size_t)NQ;             // (B,H,D,D)

    // 0) weights cast+transpose
    wt_cast_transpose<<<dim3(16, 16, 4), 256, 0, stream>>>(Wq, Wk, Wv, Wo,
                                                           WqT, WkT, WvT, WoT);
    // 1) gates + x->bf16 cast
    gates_kernel<<<NROWS, 256, 0, stream>>>(x, Wa, ba, Wb, bb, Alpha, Beta, xb);
    // 2) Q/K/V projections (bf16 in, bf16 out)
    qkv_gemm_bf16<<<dim3(INNER / 128, NROWS / 128, 3), 256, 0, stream>>>(
        xb, WqT, WkT, WvT, Qb, Kbf, Vbf);
    // 3) intra-chunk MFMA (+fused knorm): Y_intra -> Vbf, dS -> DS, decay -> Dec
    chunk_ds<<<B_SZ * NH * NCH, 256, 0, stream>>>(Qb, Kbf, Vbf, Alpha, Beta, Dec, DS);
    // 4) serial inter-chunk state recurrence; dS -> Sc in-place
    chunk_state<<<B_SZ * NH, 256, 0, stream>>>(DS, Dec, state, Sout);
    // 5) parallel Y_inter MFMA, in-place finalize of Vbf
    chunk_y<<<B_SZ * NH * NCH, 256, 0, stream>>>(Qb, DS, Vbf, Alpha);
    // 6) output projection (bf16 in, fp32 out)
    out_gemm_bf16<<<dim3(DM / 128, NROWS / 128), 256, 0, stream>>>(Vbf, WoT, out);
}

// Round 7
// 289.120 us; speedup vs baseline: 9.7863x; 1.1949x over previous
//
#include <hip/hip_runtime.h>
#include <hip/hip_bf16.h>
#include <math.h>

// Problem constants
#define B_SZ   4
#define T_LEN  2048
#define DM     1024
#define NH     16
#define DH     64
#define INNER  1024          // NH*DH
#define NROWS  (B_SZ*T_LEN)  // 8192
#define NQ     (NROWS*INNER) // elements per Q/K/V/Y buffer
#define CH     64            // chunk length
#define NCH    (T_LEN/CH)    // 32 chunks

typedef __bf16 bf16x8 __attribute__((ext_vector_type(8)));
typedef __bf16 bf16x4 __attribute__((ext_vector_type(4)));
typedef float  f32x4  __attribute__((ext_vector_type(4)));
typedef __attribute__((address_space(3))) void*       lds_vp;
typedef const __attribute__((address_space(1))) void* gbl_vp;

// Swizzled index into a 64x64 bf16 LDS tile: 8-elem blocks rotated by row>>2.
__device__ __forceinline__ int swz(int row, int col) {
    return (row << 6) + ((((col >> 3) + (row >> 2)) & 7) << 3) + (col & 7);
}

// ---------------------------------------------------------------------------
// Weight transpose + cast: W (K x N fp32, row-major) -> WT (N x K bf16).
// ---------------------------------------------------------------------------
__global__ __launch_bounds__(256) void wt_cast_transpose(const float* __restrict__ Wq,
                                                         const float* __restrict__ Wk,
                                                         const float* __restrict__ Wv,
                                                         const float* __restrict__ Wo,
                                                         __bf16* __restrict__ WqT,
                                                         __bf16* __restrict__ WkT,
                                                         __bf16* __restrict__ WvT,
                                                         __bf16* __restrict__ WoT) {
    __shared__ float tile[64][65];
    const float* W;
    __bf16* WT;
    if      (blockIdx.z == 0) { W = Wq; WT = WqT; }
    else if (blockIdx.z == 1) { W = Wk; WT = WkT; }
    else if (blockIdx.z == 2) { W = Wv; WT = WvT; }
    else                      { W = Wo; WT = WoT; }

    const int k0 = blockIdx.y * 64, n0 = blockIdx.x * 64;
    const int tr  = threadIdx.x >> 4;        // 0..15
    const int tc4 = (threadIdx.x & 15) * 4;  // 0..60

#pragma unroll
    for (int r = 0; r < 4; r++) {
        const int k = tr + 16 * r;
        const float4 v = *(const float4*)(W + (size_t)(k0 + k) * DM + n0 + tc4);
        tile[k][tc4 + 0] = v.x;
        tile[k][tc4 + 1] = v.y;
        tile[k][tc4 + 2] = v.z;
        tile[k][tc4 + 3] = v.w;
    }
    __syncthreads();
#pragma unroll
    for (int r = 0; r < 4; r++) {
        const int n = tr + 16 * r;
        bf16x4 o;
#pragma unroll
        for (int j = 0; j < 4; j++) o[j] = (__bf16)tile[tc4 + j][n];
        *(bf16x4*)(WT + (size_t)(n0 + n) * DM + k0 + tc4) = o;
    }
}

// ---------------------------------------------------------------------------
// bf16 MFMA GEMM (m97 structure): C[M x N] = A[M x K] * BT[N x K]^T.
// m0/n0 supplied by caller (XCD-swizzled).
// ---------------------------------------------------------------------------
template <typename CT>
__device__ __forceinline__ void gemm_bf16_body(const __bf16* __restrict__ A,
                                               const __bf16* __restrict__ BT,
                                               CT* __restrict__ C,
                                               int Ndim, int Kdim,
                                               int m0, int n0) {
    __shared__ __align__(16) __bf16 lA[128 * 32];
    __shared__ __align__(16) __bf16 lB[128 * 32];

    const int tid  = threadIdx.x;
    const int wid  = tid >> 6;
    const int lane = tid & 63;
    const int wm = (wid >> 1) * 64, wn = (wid & 1) * 64;

    f32x4 acc[4][4];
#pragma unroll
    for (int i = 0; i < 4; i++)
#pragma unroll
        for (int j = 0; j < 4; j++) acc[i][j] = (f32x4)0.f;

    const int srow = wid * 32 + (lane >> 2);
    const int scol = (lane & 3) * 8;
    const __bf16* gA = A  + (size_t)(m0 + srow) * Kdim + scol;
    const __bf16* gB = BT + (size_t)(n0 + srow) * Kdim + scol;

    const int qoff = (lane >> 4) * 8;
    const int frow = lane & 15;

    for (int k0 = 0; k0 < Kdim; k0 += 32) {
        __syncthreads();
#pragma unroll
        for (int i = 0; i < 2; i++) {
            __builtin_amdgcn_global_load_lds((gbl_vp)(gA + k0 + (size_t)i * 16 * Kdim),
                                             (lds_vp)(&lA[(wid * 32 + i * 16) * 32]),
                                             16, 0, 0);
            __builtin_amdgcn_global_load_lds((gbl_vp)(gB + k0 + (size_t)i * 16 * Kdim),
                                             (lds_vp)(&lB[(wid * 32 + i * 16) * 32]),
                                             16, 0, 0);
        }
        __syncthreads();

        bf16x8 af[4], bfr[4];
#pragma unroll
        for (int t = 0; t < 4; t++) {
            af[t]  = *(const bf16x8*)&lA[(wm + t * 16 + frow) * 32 + qoff];
            bfr[t] = *(const bf16x8*)&lB[(wn + t * 16 + frow) * 32 + qoff];
        }
#pragma unroll
        for (int mi = 0; mi < 4; mi++)
#pragma unroll
            for (int nj = 0; nj < 4; nj++)
                acc[mi][nj] = __builtin_amdgcn_mfma_f32_16x16x32_bf16(
                    af[mi], bfr[nj], acc[mi][nj], 0, 0, 0);
    }

    const int cr = (lane >> 4) * 4, cc = lane & 15;
#pragma unroll
    for (int mi = 0; mi < 4; mi++) {
#pragma unroll
        for (int nj = 0; nj < 4; nj++) {
            CT* Cp = C + (size_t)(m0 + wm + mi * 16 + cr) * Ndim + n0 + wn + nj * 16 + cc;
#pragma unroll
            for (int r = 0; r < 4; r++) Cp[(size_t)r * Ndim] = (CT)acc[mi][nj][r];
        }
    }
}

// XCD swizzle: linear id -> (mt, nt) s.t. each XCD (id&7, round-robin
// dispatch heuristic) owns a contiguous 8-m-tile stripe -> per-XCD L2
// working set ~2MB of A + full B panel. Pure perf heuristic; bijective.
__device__ __forceinline__ void xcd_swz(int& mt, int& nt) {
    const int id = blockIdx.y * gridDim.x + blockIdx.x;  // gridDim.x == 8
    const int xcd = id & 7, j = id >> 3;
    mt = xcd * 8 + (j >> 3);
    nt = j & 7;
}

__global__ __launch_bounds__(256) void qkv_gemm_bf16(const __bf16* __restrict__ xb,
                                                     const __bf16* __restrict__ WqT,
                                                     const __bf16* __restrict__ WkT,
                                                     const __bf16* __restrict__ WvT,
                                                     __bf16* __restrict__ Q,
                                                     __bf16* __restrict__ K_,
                                                     __bf16* __restrict__ V) {
    const __bf16* BT = (blockIdx.z == 0) ? WqT : ((blockIdx.z == 1) ? WkT : WvT);
    __bf16*       Cm = (blockIdx.z == 0) ? Q   : ((blockIdx.z == 1) ? K_  : V);
    int mt, nt; xcd_swz(mt, nt);
    gemm_bf16_body<__bf16>(xb, BT, Cm, INNER, DM, mt * 128, nt * 128);
}

__global__ __launch_bounds__(256) void out_gemm_bf16(const __bf16* __restrict__ Yb,
                                                     const __bf16* __restrict__ WoT,
                                                     float* __restrict__ Cout) {
    int mt, nt; xcd_swz(mt, nt);
    gemm_bf16_body<float>(Yb, WoT, Cout, DM, INNER, mt * 128, nt * 128);
}

// ---------------------------------------------------------------------------
// Fused gates + x cast (MFMA).  128 blocks x 256 thr; block = 64 rows.
//   lWg[col][k] = [Wa | Wb]^T bf16 (staged once, padded stride 1032)
//   per K-iter: x fp32 -> bf16 regs -> (lA tile + xb global)
//   MFMA 16x16x32: rows x [alpha|beta] cols; sigmoid epilogue ->
//   AlphaT/BetaT[h][row]  (transposed for coalesced chunk-kernel reads).
// ---------------------------------------------------------------------------
#define WGS 1032   // lWg row stride (bf16): 516 dw, 4-dw bank rotation
#define LAS 40     // lA row stride (bf16): 20 dw rotation, 16B aligned
__global__ __launch_bounds__(256) void gates_fused(const float* __restrict__ x,
                                                   const float* __restrict__ Wa,
                                                   const float* __restrict__ ba,
                                                   const float* __restrict__ Wb,
                                                   const float* __restrict__ bb,
                                                   float* __restrict__ AlphaT,
                                                   float* __restrict__ BetaT,
                                                   __bf16* __restrict__ xb) {
    __shared__ __align__(16) __bf16 lWg[32 * WGS];
    __shared__ __align__(16) __bf16 lA[64 * LAS];

    const int tid = threadIdx.x;
    const int wid = tid >> 6, lane = tid & 63;
    const int quad = lane >> 4, frow = lane & 15;
    const int m0 = blockIdx.x * 64;

    // ---- stage W^T (bf16) into LDS ----
    {
        const int kbase = tid * 4;
#pragma unroll
        for (int j = 0; j < 4; j++) {
            const int k = kbase + j;
            const float4* war = (const float4*)(Wa + (size_t)k * NH);
            const float4* wbr = (const float4*)(Wb + (size_t)k * NH);
#pragma unroll
            for (int q = 0; q < 4; q++) {
                const float4 a = war[q], bq = wbr[q];
                lWg[(q * 4 + 0) * WGS + k] = (__bf16)a.x;
                lWg[(q * 4 + 1) * WGS + k] = (__bf16)a.y;
                lWg[(q * 4 + 2) * WGS + k] = (__bf16)a.z;
                lWg[(q * 4 + 3) * WGS + k] = (__bf16)a.w;
                lWg[(16 + q * 4 + 0) * WGS + k] = (__bf16)bq.x;
                lWg[(16 + q * 4 + 1) * WGS + k] = (__bf16)bq.y;
                lWg[(16 + q * 4 + 2) * WGS + k] = (__bf16)bq.z;
                lWg[(16 + q * 4 + 3) * WGS + k] = (__bf16)bq.w;
            }
        }
    }
    const float bias_a = ba[frow];
    const float bias_b = bb[frow];

    // ---- pipelined K loop ----
    const int rrow = tid >> 2;          // 0..63
    const int rk   = (tid & 3) * 8;     // 0,8,16,24
    const float* xrow = x + (size_t)(m0 + rrow) * DM + rk;
    float4 c0 = *(const float4*)(xrow + 0);
    float4 c1 = *(const float4*)(xrow + 4);

    f32x4 acc[2];
    acc[0] = (f32x4)0.f; acc[1] = (f32x4)0.f;

    for (int k0 = 0; k0 < DM; k0 += 32) {
        __syncthreads();   // prev iter's lA reads done (also covers lWg stage)
        bf16x8 xv;
        xv[0] = (__bf16)c0.x; xv[1] = (__bf16)c0.y; xv[2] = (__bf16)c0.z; xv[3] = (__bf16)c0.w;
        xv[4] = (__bf16)c1.x; xv[5] = (__bf16)c1.y; xv[6] = (__bf16)c1.z; xv[7] = (__bf16)c1.w;
        *(bf16x8*)&lA[rrow * LAS + rk] = xv;
        *(bf16x8*)(xb + (size_t)(m0 + rrow) * DM + k0 + rk) = xv;
        if (k0 + 32 < DM) {
            c0 = *(const float4*)(xrow + k0 + 32);
            c1 = *(const float4*)(xrow + k0 + 36);
        }
        __syncthreads();
        const bf16x8 af = *(const bf16x8*)&lA[(wid * 16 + frow) * LAS + quad * 8];
#pragma unroll
        for (int ct = 0; ct < 2; ct++) {
            const bf16x8 bf = *(const bf16x8*)&lWg[(ct * 16 + frow) * WGS + k0 + quad * 8];
            acc[ct] = __builtin_amdgcn_mfma_f32_16x16x32_bf16(af, bf, acc[ct], 0, 0, 0);
        }
    }

    // ---- sigmoid epilogue, transposed store ----
#pragma unroll
    for (int ct = 0; ct < 2; ct++) {
        const float bias = (ct == 0) ? bias_a : bias_b;
        float* dst = (ct == 0) ? AlphaT : BetaT;
#pragma unroll
        for (int r = 0; r < 4; r++) {
            const int row = m0 + wid * 16 + quad * 4 + r;
            const float s = acc[ct][r] + bias;
            dst[(size_t)frow * NROWS + row] = 1.f / (1.f + __expf(-s));
        }
    }
}

// ---------------------------------------------------------------------------
// Pass A (MFMA, bf16 I/O): per (b,h,c), 256 threads = 4 waves.
//   K rows L2-normalized in-register (knorm fused).
//   G = Q K^T ; A = mask*exp(la_t-la_s)*b_s*G ; Y_intra = A V -> V (bf16)
//   dS = sum_s swd_s v_s k_s^T -> DS (fp32); exp(la_t) -> ExpT; decay -> Dec
// ---------------------------------------------------------------------------
__global__ __launch_bounds__(256) void chunk_ds(const __bf16* __restrict__ Q,
                                                const __bf16* __restrict__ K,
                                                __bf16* __restrict__ V,
                                                const float* __restrict__ AlphaT,
                                                const float* __restrict__ BetaT,
                                                float* __restrict__ Dec,
                                                float* __restrict__ DS,
                                                float* __restrict__ ExpT) {
    __shared__ __align__(16) __bf16 Qb[64 * 64];
    __shared__ __align__(16) __bf16 Kb[64 * 64];
    __shared__ __align__(16) __bf16 KTs[64 * 64];  // [j][s] = swd_s * kn[s][j]
    __shared__ __align__(16) __bf16 VTb[64 * 64];  // [i][s] = V[s][i]
    __shared__ __align__(16) __bf16 Ab[64 * 64];   // [t][s]
    __shared__ float sla[64], sb[64], swd[64];

    const int blk = blockIdx.x;
    const int c = blk & 31, h = (blk >> 5) & 15, b = blk >> 9;
    const int t0 = c * CH;
    const int tid = threadIdx.x;
    const int wid = tid >> 6, lane = tid & 63;
    const size_t rowbase = ((size_t)(b * T_LEN + t0) * NH + h) * DH;

    // prefetch (16B bf16x8 per matrix per round)
    const int srow = tid >> 3;          // 0..31
    const int scol = (tid & 7) * 8;     // 0..56
    bf16x8 q8[2], k8[2], v8[2];
#pragma unroll
    for (int r = 0; r < 2; r++) {
        const size_t g = rowbase + (size_t)(srow + 32 * r) * INNER + scol;
        q8[r] = *(const bf16x8*)(Q + g);
        k8[r] = *(const bf16x8*)(K + g);
        v8[r] = *(const bf16x8*)(V + g);
    }

    // gates: prefix-sum of log(alpha) over the chunk (wave 0, coalesced)
    if (tid < 64) {
        const int t = tid;
        const size_t gaT = (size_t)h * NROWS + b * T_LEN + t0 + t;
        const float a  = AlphaT[gaT];
        const float bt = BetaT[gaT];
        float xx = logf(a);
#pragma unroll
        for (int off = 1; off < 64; off <<= 1) {
            const float y = __shfl_up(xx, off, 64);
            if (t >= off) xx += y;
        }
        const float la63 = __shfl(xx, 63, 64);
        sla[t] = xx;
        sb[t]  = bt;
        swd[t] = bt * __expf(la63 - xx);
        ExpT[gaT] = __expf(xx);
        if (t == 63) Dec[(size_t)(b * NH + h) * NCH + c] = __expf(la63);
    }
    __syncthreads();

    // stage to LDS: normalize k rows (8 lanes per row -> 3 shfl_xor)
#pragma unroll
    for (int r = 0; r < 2; r++) {
        const int row = srow + 32 * r;
        float kf[8];
        float ss = 0.f;
#pragma unroll
        for (int j = 0; j < 8; j++) { kf[j] = (float)k8[r][j]; ss += kf[j] * kf[j]; }
        ss += __shfl_xor(ss, 1, 64);
        ss += __shfl_xor(ss, 2, 64);
        ss += __shfl_xor(ss, 4, 64);
        const float scale = 1.f / fmaxf(sqrtf(ss), 1e-12f);
        const float w = swd[row];
        bf16x8 kn8;
#pragma unroll
        for (int j = 0; j < 8; j++) {
            const float kn = kf[j] * scale;
            kn8[j] = (__bf16)kn;
            KTs[swz(scol + j, row)] = (__bf16)(w * kn);
            VTb[swz(scol + j, row)] = v8[r][j];
        }
        *(bf16x8*)&Qb[swz(row, scol)] = q8[r];
        *(bf16x8*)&Kb[swz(row, scol)] = kn8;
    }
    __syncthreads();

    const int quad = lane >> 4;
    const int frow = lane & 15;
    const int tw = wid * 16;   // this wave's 16-row output stripe

    // ---- G = Q K^T ----
    f32x4 accG[4];
#pragma unroll
    for (int i = 0; i < 4; i++) accG[i] = (f32x4)0.f;
#pragma unroll
    for (int ks = 0; ks < 2; ks++) {
        const int ko = quad * 8 + 32 * ks;
        const bf16x8 aq = *(const bf16x8*)&Qb[swz(tw + frow, ko)];
#pragma unroll
        for (int st = 0; st < 4; st++) {
            const bf16x8 bk = *(const bf16x8*)&Kb[swz(st * 16 + frow, ko)];
            accG[st] = __builtin_amdgcn_mfma_f32_16x16x32_bf16(aq, bk, accG[st], 0, 0, 0);
        }
    }
    // ---- mask -> Ab (C layout: row=quad*4+r, col=frow) ----
#pragma unroll
    for (int st = 0; st < 4; st++) {
#pragma unroll
        for (int r = 0; r < 4; r++) {
            const int t = tw + quad * 4 + r;
            const int s = st * 16 + frow;
            const float av = (s <= t) ? __expf(sla[t] - sla[s]) * sb[s] * accG[st][r] : 0.f;
            Ab[swz(t, s)] = (__bf16)av;
        }
    }
    __syncthreads();

    // ---- Y_intra = A V  and  dS = VT * KTs^T ----
    f32x4 accY[4], accD[4];
#pragma unroll
    for (int i = 0; i < 4; i++) { accY[i] = (f32x4)0.f; accD[i] = (f32x4)0.f; }
#pragma unroll
    for (int ks = 0; ks < 2; ks++) {
        const int ko = quad * 8 + 32 * ks;
        const bf16x8 aA = *(const bf16x8*)&Ab[swz(tw + frow, ko)];
        const bf16x8 aV = *(const bf16x8*)&VTb[swz(tw + frow, ko)];
#pragma unroll
        for (int jt = 0; jt < 4; jt++) {
            const bf16x8 bv = *(const bf16x8*)&VTb[swz(jt * 16 + frow, ko)];
            const bf16x8 bk = *(const bf16x8*)&KTs[swz(jt * 16 + frow, ko)];
            accY[jt] = __builtin_amdgcn_mfma_f32_16x16x32_bf16(aA, bv, accY[jt], 0, 0, 0);
            accD[jt] = __builtin_amdgcn_mfma_f32_16x16x32_bf16(aV, bk, accD[jt], 0, 0, 0);
        }
    }
    // write Y_intra (bf16) over V, dS (fp32) to DS
#pragma unroll
    for (int jt = 0; jt < 4; jt++) {
#pragma unroll
        for (int r = 0; r < 4; r++) {
            const int row = tw + quad * 4 + r;
            const size_t g = rowbase + (size_t)row * INNER + jt * 16 + frow;
            V[g]  = (__bf16)accY[jt][r];
            DS[g] = accD[jt][r];
        }
    }
}

// ---------------------------------------------------------------------------
// Pass B1 (serial, tiny): S_{c+1} = Dec_c * S_c + dS_c over 32 chunks per
// (b,h).  Writes each PRE-update state S_c as bf16 to ScB (for chunk_y).
// ---------------------------------------------------------------------------
__global__ __launch_bounds__(256) void chunk_state(const float* __restrict__ DS,
                                                   const float* __restrict__ Dec,
                                                   const float* __restrict__ state_in,
                                                   float* __restrict__ state_out,
                                                   __bf16* __restrict__ ScB) {
    const int blk = blockIdx.x;          // (b,h)
    const int b = blk >> 4, h = blk & 15;
    const int tid = threadIdx.x;
    const int w = tid >> 6;
    const int l = tid & 63;

    float S[16];
    {
        const float* st = state_in + ((size_t)(b * NH + h) * DH + l) * DH + 16 * w;
#pragma unroll
        for (int j4 = 0; j4 < 4; j4++)
            *(float4*)&S[4 * j4] = *(const float4*)(st + 4 * j4);
    }

    for (int c = 0; c < NCH; c++) {
        const int t0 = c * CH;
        const float decay = Dec[(size_t)(b * NH + h) * NCH + c];
        const size_t off = ((size_t)(b * T_LEN + t0 + l) * NH + h) * DH + 16 * w;
        const float* ds = DS + off;
        __bf16* sc = ScB + off;
        float4 dv[4];
#pragma unroll
        for (int j4 = 0; j4 < 4; j4++) dv[j4] = *(const float4*)(ds + 4 * j4);
#pragma unroll
        for (int j4 = 0; j4 < 4; j4++) {
            bf16x4 o;
            o[0] = (__bf16)S[4 * j4 + 0]; o[1] = (__bf16)S[4 * j4 + 1];
            o[2] = (__bf16)S[4 * j4 + 2]; o[3] = (__bf16)S[4 * j4 + 3];
            *(bf16x4*)(sc + 4 * j4) = o;
        }
#pragma unroll
        for (int j4 = 0; j4 < 4; j4++) {
            S[4 * j4 + 0] = decay * S[4 * j4 + 0] + dv[j4].x;
            S[4 * j4 + 1] = decay * S[4 * j4 + 1] + dv[j4].y;
            S[4 * j4 + 2] = decay * S[4 * j4 + 2] + dv[j4].z;
            S[4 * j4 + 3] = decay * S[4 * j4 + 3] + dv[j4].w;
        }
    }

    float* so = state_out + ((size_t)(b * NH + h) * DH + l) * DH + 16 * w;
#pragma unroll
    for (int j4 = 0; j4 < 4; j4++)
        *(float4*)(so + 4 * j4) = *(const float4*)&S[4 * j4];
}

// ---------------------------------------------------------------------------
// Pass B2 (MFMA): Yb[t][i] = bf16( Yb[t][i] + ExpT[t]*sum_j Q[t][j]Sc[i][j] )
// in-place over the Y_intra buffer.  Per (b,h,c), 256 threads = 4 waves.
// ---------------------------------------------------------------------------
__global__ __launch_bounds__(256) void chunk_y(const __bf16* __restrict__ Q,
                                               const __bf16* __restrict__ ScB,
                                               __bf16* __restrict__ Yb,
                                               const float* __restrict__ ExpT) {
    __shared__ __align__(16) __bf16 Qb[64 * 64];
    __shared__ __align__(16) __bf16 Scb[64 * 64];
    __shared__ float sexp[64];

    const int blk = blockIdx.x;
    const int c = blk & 31, h = (blk >> 5) & 15, b = blk >> 9;
    const int t0 = c * CH;
    const int tid = threadIdx.x;
    const int wid = tid >> 6, lane = tid & 63;
    const size_t rowbase = ((size_t)(b * T_LEN + t0) * NH + h) * DH;

    // prefetch Q / Sc (bf16x8)
    const int srow = tid >> 3;
    const int scol = (tid & 7) * 8;
    bf16x8 q8[2], s8[2];
#pragma unroll
    for (int r = 0; r < 2; r++) {
        const size_t g = rowbase + (size_t)(srow + 32 * r) * INNER + scol;
        q8[r] = *(const bf16x8*)(Q + g);
        s8[r] = *(const bf16x8*)(ScB + g);
    }

    if (tid < 64)
        sexp[tid] = ExpT[(size_t)h * NROWS + b * T_LEN + t0 + tid];

#pragma unroll
    for (int r = 0; r < 2; r++) {
        *(bf16x8*)&Qb[swz(srow + 32 * r, scol)]  = q8[r];
        *(bf16x8*)&Scb[swz(srow + 32 * r, scol)] = s8[r];
    }
    __syncthreads();

    const int quad = lane >> 4;
    const int frow = lane & 15;
    const int tw = wid * 16;

    f32x4 accU[4];
#pragma unroll
    for (int i = 0; i < 4; i++) accU[i] = (f32x4)0.f;
#pragma unroll
    for (int ks = 0; ks < 2; ks++) {
        const int ko = quad * 8 + 32 * ks;
        const bf16x8 aq = *(const bf16x8*)&Qb[swz(tw + frow, ko)];
#pragma unroll
        for (int it = 0; it < 4; it++) {
            const bf16x8 bs = *(const bf16x8*)&Scb[swz(it * 16 + frow, ko)];
            accU[it] = __builtin_amdgcn_mfma_f32_16x16x32_bf16(aq, bs, accU[it], 0, 0, 0);
        }
    }

#pragma unroll
    for (int it = 0; it < 4; it++) {
#pragma unroll
        for (int r = 0; r < 4; r++) {
            const int t = tw + quad * 4 + r;
            const size_t g = rowbase + (size_t)t * INNER + it * 16 + frow;
            Yb[g] = (__bf16)(sexp[t] * accU[it][r] + (float)Yb[g]);
        }
    }
}

// ---------------------------------------------------------------------------
extern "C" void kernel_launch(void* const* d_in, const int* in_sizes, int n_in,
                              void* d_out, int out_size, void* d_ws, size_t ws_size,
                              hipStream_t stream) {
    const float* x     = (const float*)d_in[0];
    const float* state = (const float*)d_in[1];
    const float* Wq    = (const float*)d_in[2];
    const float* Wk    = (const float*)d_in[3];
    const float* Wv    = (const float*)d_in[4];
    const float* Wa    = (const float*)d_in[5];
    const float* ba    = (const float*)d_in[6];
    const float* Wb    = (const float*)d_in[7];
    const float* bb    = (const float*)d_in[8];
    const float* Wo    = (const float*)d_in[9];

    __bf16* Qb    = (__bf16*)d_ws;               // NQ bf16 (raw q, preserved)
    __bf16* Kbf   = Qb + (size_t)NQ;             // NQ bf16 (raw k)
    __bf16* Vbf   = Kbf + (size_t)NQ;            // NQ bf16 (v -> Y_intra -> Y)
    float*  DS    = (float*)(Vbf + (size_t)NQ);  // NQ fp32 (dS)
    float*  AlphaT= DS + (size_t)NQ;             // [NH][NROWS]
    float*  BetaT = AlphaT + (size_t)NROWS * NH;
    float*  ExpT  = BetaT + (size_t)NROWS * NH;  // [NH][NROWS] exp(la_t)
    float*  Dec   = ExpT + (size_t)NROWS * NH;   // per-chunk decay
    __bf16* xb    = (__bf16*)(Dec + (size_t)B_SZ * NH * NCH);
    __bf16* ScB   = xb;                          // reuse: xb dead after qkv gemm
    __bf16* WqT   = xb + (size_t)NQ;
    __bf16* WkT   = WqT + (size_t)DM * INNER;
    __bf16* WvT   = WkT + (size_t)DM * INNER;
    __bf16* WoT   = WvT + (size_t)DM * INNER;

    float* out  = (float*)d_out;                // (B,T,DM)
    float* Sout = out + (size_t)NQ;             // (B,H,D,D)

    // 0) weights cast+transpose
    wt_cast_transpose<<<dim3(16, 16, 4), 256, 0, stream>>>(Wq, Wk, Wv, Wo,
                                                           WqT, WkT, WvT, WoT);
    // 1) fused gates (MFMA) + x->bf16 cast
    gates_fused<<<NROWS / 64, 256, 0, stream>>>(x, Wa, ba, Wb, bb,
                                                AlphaT, BetaT, xb);
    // 2) Q/K/V projections (bf16 in, bf16 out, XCD-swizzled)
    qkv_gemm_bf16<<<dim3(INNER / 128, NROWS / 128, 3), 256, 0, stream>>>(
        xb, WqT, WkT, WvT, Qb, Kbf, Vbf);
    // 3) intra-chunk MFMA (+fused knorm): Y_intra -> Vbf, dS -> DS
    chunk_ds<<<B_SZ * NH * NCH, 256, 0, stream>>>(Qb, Kbf, Vbf, AlphaT, BetaT,
                                                  Dec, DS, ExpT);
    // 4) serial inter-chunk state recurrence; Sc -> ScB (bf16)
    chunk_state<<<B_SZ * NH, 256, 0, stream>>>(DS, Dec, state, Sout, ScB);
    // 5) parallel Y_inter MFMA, in-place finalize of Vbf
    chunk_y<<<B_SZ * NH * NCH, 256, 0, stream>>>(Qb, ScB, Vbf, ExpT);
    // 6) output projection (bf16 in, fp32 out, XCD-swizzled)
    out_gemm_bf16<<<dim3(DM / 128, NROWS / 128), 256, 0, stream>>>(Vbf, WoT, out);
}